// Round 5
// baseline (219.453 us; speedup 1.0000x reference)
//
#include <hip/hip_runtime.h>
#include <hip/hip_bf16.h>
#include <stdint.h>

// Problem constants (B=1). I/O dtype: fp32. Internals bf16 (MFMA path).
#define S_LEN 2048
#define HID   2048
#define NQH   32
#define NKVH  8
#define HD    64
#define QKV_O 3072      // (32 + 2*8) * 64
#define K_COL 2048      // col offset of K block in qkv row
#define V_COL 2560      // col offset of V block in qkv row

typedef unsigned short ushort_t;
typedef __bf16 bf16x8 __attribute__((ext_vector_type(8)));
typedef float  f32x4  __attribute__((ext_vector_type(4)));

#define GLB(p) ((const __attribute__((address_space(1))) void*)(p))
#define LDSP(p) ((__attribute__((address_space(3))) void*)(p))

__device__ __forceinline__ ushort_t f2bf(float f) {
    unsigned int x = __float_as_uint(f);
    unsigned int r = (x + 0x7fffu + ((x >> 16) & 1u)) >> 16;   // RNE
    return (ushort_t)r;
}
__device__ __forceinline__ unsigned int pk_bf16(float a, float b) {
    __hip_bfloat162 h = __float22bfloat162_rn(make_float2(a, b));
    unsigned int r;
    __builtin_memcpy(&r, &h, 4);
    return r;
}
__device__ __forceinline__ void unpack8(float* dst, uint4 u) {
    dst[0] = __uint_as_float(u.x << 16); dst[1] = __uint_as_float(u.x & 0xffff0000u);
    dst[2] = __uint_as_float(u.y << 16); dst[3] = __uint_as_float(u.y & 0xffff0000u);
    dst[4] = __uint_as_float(u.z << 16); dst[5] = __uint_as_float(u.z & 0xffff0000u);
    dst[6] = __uint_as_float(u.w << 16); dst[7] = __uint_as_float(u.w & 0xffff0000u);
}

// ---------------------------------------------------------------------------
// convert3: fp32 -> bf16 for x, w_qkv, w_out (unchanged)
// ---------------------------------------------------------------------------
#define XN8 (S_LEN * HID / 8)          // 524288
#define QN8 (QKV_O * HID / 8)          // 786432
#define ON8 (HID * HID / 8)            // 524288

__global__ __launch_bounds__(256) void convert3(
    const float* __restrict__ x, const float* __restrict__ wq,
    const float* __restrict__ wo, ushort_t* __restrict__ xb,
    ushort_t* __restrict__ wqb, ushort_t* __restrict__ wob) {
    int i = blockIdx.x * 256 + threadIdx.x;
    const float* s; ushort_t* d; int off;
    if (i < XN8)            { s = x;  d = xb;  off = i; }
    else if (i < XN8 + QN8) { s = wq; d = wqb; off = i - XN8; }
    else                    { s = wo; d = wob; off = i - XN8 - QN8; }
    const float4* sp = (const float4*)s + (size_t)off * 2;
    float4 a = sp[0], b = sp[1];
    *(uint4*)(d + (size_t)off * 8) = make_uint4(
        pk_bf16(a.x, a.y), pk_bf16(a.z, a.w),
        pk_bf16(b.x, b.y), pk_bf16(b.z, b.w));
}

// ---------------------------------------------------------------------------
// gemm128: m97-class 128x128 tile, BK=64, XOR-swizzled global_load_lds
// staging (8 DMA ops/wave/k-step), acc[4][4]/wave. Upgraded from the round-0
// 64x128 tile: +2x MFMA density per LDS read, -33% B-panel re-reads
// (M/128=16 passes instead of 32).
// ROPE: fused in-lane RoPE epilogue for q/k tiles (bn < V_COL).
// VT:   V tiles (bn >= V_COL) stored transposed to VtG[vcol][seq].
// ---------------------------------------------------------------------------
template<bool CF32, bool ROPE, bool VT>
__global__ __launch_bounds__(256) void gemm128(
    const ushort_t* __restrict__ A, const ushort_t* __restrict__ Bt,
    void* __restrict__ Cp, int M, int N, int K,
    const float* __restrict__ cs, const float* __restrict__ sn,
    ushort_t* __restrict__ VtG) {
    __shared__ ushort_t As[128][64];    // 16 KB
    __shared__ ushort_t Bs[128][64];    // 16 KB

    const int t    = threadIdx.x;
    const int wave = t >> 6;
    const int lane = t & 63;
    const int quad = lane >> 4;
    const int l16  = lane & 15;
    const int wm   = (wave >> 1) << 6;  // 0 / 64
    const int wn   = (wave & 1)  << 6;  // 0 / 64
    const int bm   = blockIdx.y * 128;
    const int bn   = blockIdx.x * 128;
    const int lr   = lane >> 3;                 // row-in-group 0..7
    const int lc   = ((lane & 7) ^ lr) << 3;    // pre-swizzled source chunk

    f32x4 acc[4][4];
    #pragma unroll
    for (int i = 0; i < 4; i++)
        #pragma unroll
        for (int j = 0; j < 4; j++) {
            f32x4 z = {0.f, 0.f, 0.f, 0.f};
            acc[i][j] = z;
        }

    // each wave stages 32 rows of A and 32 rows of B per k-step (4+4 DMA ops)
    const ushort_t* a0 = &A[(size_t)(bm + wave * 32 + lr) * K + lc];
    const ushort_t* b0 = &Bt[(size_t)(bn + wave * 32 + lr) * K + lc];
    const size_t r8 = (size_t)8 * K;

    for (int k0 = 0; k0 < K; k0 += 64) {
        __syncthreads();
        #pragma unroll
        for (int p = 0; p < 4; p++) {
            __builtin_amdgcn_global_load_lds(GLB(a0 + k0 + p * r8),
                                             LDSP(&As[wave * 32 + p * 8][0]), 16, 0, 0);
            __builtin_amdgcn_global_load_lds(GLB(b0 + k0 + p * r8),
                                             LDSP(&Bs[wave * 32 + p * 8][0]), 16, 0, 0);
        }
        __syncthreads();

        #pragma unroll
        for (int ks = 0; ks < 2; ks++) {
            const int ca = (((ks << 2) + quad) ^ (l16 & 7)) << 3;
            bf16x8 af[4], bfr[4];
            #pragma unroll
            for (int i = 0; i < 4; i++)
                af[i] = *(const bf16x8*)&As[wm + i * 16 + l16][ca];
            #pragma unroll
            for (int j = 0; j < 4; j++)
                bfr[j] = *(const bf16x8*)&Bs[wn + j * 16 + l16][ca];

            #pragma unroll
            for (int i = 0; i < 4; i++)
                #pragma unroll
                for (int j = 0; j < 4; j++)
                    acc[i][j] = __builtin_amdgcn_mfma_f32_16x16x32_bf16(
                        af[i], bfr[j], acc[i][j], 0, 0, 0);
        }
    }

    // Epilogue: C/D layout col=lane&15 (+j*16), row=quad*4+reg
    if (ROPE && bn < V_COL) {
        // q/k tile: rotate-half RoPE in-lane (partner d+-32 = frag nd+-2).
        // wn in {0,64}, bn mult of 128 -> each wave's 64-col span = 1 head.
        #pragma unroll
        for (int i = 0; i < 4; i++)
            #pragma unroll
            for (int r = 0; r < 4; r++) {
                const int srow = bm + wm + i * 16 + quad * 4 + r;
                float cv[4], sv[4], o[4];
                #pragma unroll
                for (int nd = 0; nd < 4; nd++) {
                    const int d = nd * 16 + l16;
                    cv[nd] = cs[srow * HD + d];
                    sv[nd] = sn[srow * HD + d];
                }
                o[0] = acc[i][0][r] * cv[0] - acc[i][2][r] * sv[0];
                o[1] = acc[i][1][r] * cv[1] - acc[i][3][r] * sv[1];
                o[2] = acc[i][2][r] * cv[2] + acc[i][0][r] * sv[2];
                o[3] = acc[i][3][r] * cv[3] + acc[i][1][r] * sv[3];
                #pragma unroll
                for (int nd = 0; nd < 4; nd++) {
                    const int col = bn + wn + nd * 16 + l16;
                    ((ushort_t*)Cp)[(size_t)srow * N + col] = f2bf(o[nd]);
                }
            }
    } else if (VT && bn >= V_COL) {
        // V tile: write transposed to VtG[vcol][seq] (b64 packed rows)
        #pragma unroll
        for (int i = 0; i < 4; i++) {
            const int srow0 = bm + wm + i * 16 + quad * 4;
            #pragma unroll
            for (int nd = 0; nd < 4; nd++) {
                const int vcol = bn + wn + nd * 16 + l16 - V_COL;
                uint2 w2 = make_uint2(
                    pk_bf16(acc[i][nd][0], acc[i][nd][1]),
                    pk_bf16(acc[i][nd][2], acc[i][nd][3]));
                *(uint2*)&VtG[(size_t)vcol * S_LEN + srow0] = w2;
            }
        }
    } else {
        #pragma unroll
        for (int i = 0; i < 4; i++)
            #pragma unroll
            for (int j = 0; j < 4; j++)
                #pragma unroll
                for (int r = 0; r < 4; r++) {
                    int row = bm + wm + i * 16 + quad * 4 + r;
                    int col = bn + wn + j * 16 + l16;
                    if (CF32)
                        ((float*)Cp)[(size_t)row * N + col] = acc[i][j][r];
                    else
                        ((ushort_t*)Cp)[(size_t)row * N + col] = f2bf(acc[i][j][r]);
                }
    }
}

// ---------------------------------------------------------------------------
// Fallback GEMM with fused fp32->bf16 staging (small-ws path; unchanged)
// ---------------------------------------------------------------------------
template<bool AF32, bool BF32, bool CF32>
__global__ __launch_bounds__(256) void gemm_bt(
    const void* __restrict__ Ap, const void* __restrict__ Bp,
    void* __restrict__ Cp, int M, int N, int K) {
    __shared__ ushort_t As[128][40];
    __shared__ ushort_t Bs[128][40];

    const int t    = threadIdx.x;
    const int wave = t >> 6;
    const int lane = t & 63;
    const int quad = lane >> 4;
    const int l16  = lane & 15;
    const int wm   = (wave >> 1) << 6;
    const int wn   = (wave & 1)  << 6;
    const int bm   = blockIdx.y * 128;
    const int bn   = blockIdx.x * 128;
    const int sr   = t >> 2;
    const int sc   = (t & 3) << 3;

    f32x4 acc[4][4];
    #pragma unroll
    for (int i = 0; i < 4; i++)
        #pragma unroll
        for (int j = 0; j < 4; j++) {
            f32x4 z = {0.f, 0.f, 0.f, 0.f};
            acc[i][j] = z;
        }

    for (int k0 = 0; k0 < K; k0 += 32) {
        __syncthreads();
        if (AF32) {
            const float* A = (const float*)Ap;
            const float* p0 = &A[(size_t)(bm + sr) * K + k0 + sc];
            const float* p1 = &A[(size_t)(bm + sr + 64) * K + k0 + sc];
            float4 a0 = *(const float4*)p0, a1 = *(const float4*)(p0 + 4);
            float4 b0 = *(const float4*)p1, b1 = *(const float4*)(p1 + 4);
            *(uint4*)&As[sr][sc] = make_uint4(
                pk_bf16(a0.x, a0.y), pk_bf16(a0.z, a0.w),
                pk_bf16(a1.x, a1.y), pk_bf16(a1.z, a1.w));
            *(uint4*)&As[sr + 64][sc] = make_uint4(
                pk_bf16(b0.x, b0.y), pk_bf16(b0.z, b0.w),
                pk_bf16(b1.x, b1.y), pk_bf16(b1.z, b1.w));
        } else {
            const ushort_t* A = (const ushort_t*)Ap;
            *(uint4*)&As[sr][sc]      = *(const uint4*)&A[(size_t)(bm + sr) * K + k0 + sc];
            *(uint4*)&As[sr + 64][sc] = *(const uint4*)&A[(size_t)(bm + sr + 64) * K + k0 + sc];
        }
        if (BF32) {
            const float* B = (const float*)Bp;
            const float* p0 = &B[(size_t)(bn + sr) * K + k0 + sc];
            const float* p1 = &B[(size_t)(bn + sr + 64) * K + k0 + sc];
            float4 a0 = *(const float4*)p0, a1 = *(const float4*)(p0 + 4);
            float4 b0 = *(const float4*)p1, b1 = *(const float4*)(p1 + 4);
            *(uint4*)&Bs[sr][sc] = make_uint4(
                pk_bf16(a0.x, a0.y), pk_bf16(a0.z, a0.w),
                pk_bf16(a1.x, a1.y), pk_bf16(a1.z, a1.w));
            *(uint4*)&Bs[sr + 64][sc] = make_uint4(
                pk_bf16(b0.x, b0.y), pk_bf16(b0.z, b0.w),
                pk_bf16(b1.x, b1.y), pk_bf16(b1.z, b1.w));
        } else {
            const ushort_t* B = (const ushort_t*)Bp;
            *(uint4*)&Bs[sr][sc]      = *(const uint4*)&B[(size_t)(bn + sr) * K + k0 + sc];
            *(uint4*)&Bs[sr + 64][sc] = *(const uint4*)&B[(size_t)(bn + sr + 64) * K + k0 + sc];
        }
        __syncthreads();

        bf16x8 af[4], bfr[4];
        #pragma unroll
        for (int i = 0; i < 4; i++)
            af[i] = *(const bf16x8*)&As[wm + i * 16 + l16][quad * 8];
        #pragma unroll
        for (int j = 0; j < 4; j++)
            bfr[j] = *(const bf16x8*)&Bs[wn + j * 16 + l16][quad * 8];

        #pragma unroll
        for (int i = 0; i < 4; i++)
            #pragma unroll
            for (int j = 0; j < 4; j++)
                acc[i][j] = __builtin_amdgcn_mfma_f32_16x16x32_bf16(
                    af[i], bfr[j], acc[i][j], 0, 0, 0);
    }

    #pragma unroll
    for (int i = 0; i < 4; i++)
        #pragma unroll
        for (int j = 0; j < 4; j++)
            #pragma unroll
            for (int r = 0; r < 4; r++) {
                int row = bm + wm + i * 16 + quad * 4 + r;
                int col = bn + wn + j * 16 + l16;
                if (CF32)
                    ((float*)Cp)[(size_t)row * N + col] = acc[i][j][r];
                else
                    ((ushort_t*)Cp)[(size_t)row * N + col] = f2bf(acc[i][j][r]);
            }
}

// ---------------------------------------------------------------------------
// RoPE standalone (fallback path only)
// ---------------------------------------------------------------------------
__global__ __launch_bounds__(256) void rope_kernel(
    ushort_t* __restrict__ qkv, const float* __restrict__ cs,
    const float* __restrict__ sn) {
    int idx = blockIdx.x * 256 + threadIdx.x;
    if (idx >= S_LEN * (NQH + NKVH)) return;
    int s  = idx / (NQH + NKVH);
    int hh = idx - s * (NQH + NKVH);

    ushort_t* p = &qkv[(size_t)s * QKV_O + hh * HD];
    const uint4* p4 = (const uint4*)p;
    float v[HD], c[HD], sv[HD];
    #pragma unroll
    for (int b = 0; b < 8; b++) unpack8(&v[b * 8], p4[b]);
    const float4* c4 = (const float4*)&cs[s * HD];
    const float4* s4 = (const float4*)&sn[s * HD];
    #pragma unroll
    for (int b = 0; b < 16; b++) {
        ((float4*)c)[b]  = c4[b];
        ((float4*)sv)[b] = s4[b];
    }
    float o[HD];
    #pragma unroll
    for (int d = 0; d < 32; d++) {
        o[d]      = v[d] * c[d]           - v[d + 32] * sv[d];
        o[d + 32] = v[d + 32] * c[d + 32] + v[d]      * sv[d + 32];
    }
    unsigned int* pw = (unsigned int*)p;
    #pragma unroll
    for (int d = 0; d < HD; d += 2)
        pw[d >> 1] = pk_bf16(o[d], o[d + 1]);
}

// ---------------------------------------------------------------------------
// attn_v5: round-12/13 kernel (fallback paths; reads V from qkv)
// ---------------------------------------------------------------------------
__global__ __launch_bounds__(256) void attn_v5(
    const ushort_t* __restrict__ qkv, ushort_t* __restrict__ O) {
    const int bx   = blockIdx.x;
    const int h    = bx & 31;
    const int p    = bx >> 5;
    const int kvh  = h >> 2;
    const int q0d  = (31 - p) * 64;
    const int q0s  = p * 64;
    const int tid  = threadIdx.x;
    const int wave = tid >> 6;
    const int lane = tid & 63;
    const int quad = lane >> 4;
    const int l16  = lane & 15;

    __shared__ __align__(16) ushort_t Ks[2][64][72];
    __shared__ __align__(16) ushort_t Vt[2][64][72];
    __shared__ __align__(16) ushort_t Pl[4][32][72];

    const int rowbase0 = q0d + wave * 16;
    const int rowbase1 = q0s + wave * 16;

    bf16x8 bq[2][2];
    #pragma unroll
    for (int mi = 0; mi < 2; mi++) {
        const int rb = (mi == 0) ? rowbase0 : rowbase1;
        #pragma unroll
        for (int ks = 0; ks < 2; ks++) {
            uint4 u = *(const uint4*)&qkv[(size_t)(rb + l16) * QKV_O
                                          + h * HD + ks * 32 + quad * 8];
            float f[8]; unpack8(f, u);
            uint4 w = make_uint4(
                pk_bf16(f[0] * 0.125f, f[1] * 0.125f),
                pk_bf16(f[2] * 0.125f, f[3] * 0.125f),
                pk_bf16(f[4] * 0.125f, f[5] * 0.125f),
                pk_bf16(f[6] * 0.125f, f[7] * 0.125f));
            __builtin_memcpy(&bq[mi][ks], &w, 16);
        }
    }

    bf16x8 ones;
    #pragma unroll
    for (int e = 0; e < 8; e++) ones[e] = (__bf16)1.0f;

    f32x4 acc_o[2][4];
    f32x4 acc_l[2];
    #pragma unroll
    for (int mi = 0; mi < 2; mi++) {
        f32x4 z = {0.f, 0.f, 0.f, 0.f};
        acc_l[mi] = z;
        #pragma unroll
        for (int n = 0; n < 4; n++) acc_o[mi][n] = z;
    }

    const int nt = 32 - p;
    const int sr = tid >> 2;
    const int sc = (tid & 3) << 4;

    {
        const ushort_t* kp = &qkv[(size_t)sr * QKV_O + K_COL + kvh * HD + sc];
        *(uint4*)&Ks[0][sr][sc]     = *(const uint4*)kp;
        *(uint4*)&Ks[0][sr][sc + 8] = *(const uint4*)(kp + 8);
        const ushort_t* vp = &qkv[(size_t)sr * QKV_O + V_COL + kvh * HD + sc];
        ushort_t tmp[16];
        *(uint4*)&tmp[0] = *(const uint4*)vp;
        *(uint4*)&tmp[8] = *(const uint4*)(vp + 8);
        #pragma unroll
        for (int e = 0; e < 16; e++) {
            int d = sc + e;
            Vt[0][d][(sr + 8 * (d >> 3)) & 63] = tmp[e];
        }
    }
    __syncthreads();

    for (int t = 0; t < nt; t++) {
        const int cur = t & 1, nxt = cur ^ 1;
        const int j0 = t * 64;
        const bool hasNext = (t + 1 < nt);

        uint4 ka, kb, va, vb;
        if (hasNext) {
            const size_t rbase = (size_t)(j0 + 64 + sr) * QKV_O;
            const ushort_t* kp = &qkv[rbase + K_COL + kvh * HD + sc];
            ka = *(const uint4*)kp; kb = *(const uint4*)(kp + 8);
            const ushort_t* vp = &qkv[rbase + V_COL + kvh * HD + sc];
            va = *(const uint4*)vp; vb = *(const uint4*)(vp + 8);
        }

        const bool sact = (t <= p);

        f32x4 st[2][4];
        #pragma unroll
        for (int mi = 0; mi < 2; mi++)
            #pragma unroll
            for (int nk = 0; nk < 4; nk++) {
                f32x4 z = {0.f, 0.f, 0.f, 0.f};
                st[mi][nk] = z;
            }
        #pragma unroll
        for (int ks = 0; ks < 2; ks++) {
            bf16x8 ak[4];
            #pragma unroll
            for (int nk = 0; nk < 4; nk++)
                ak[nk] = *(const bf16x8*)&Ks[cur][nk * 16 + l16][ks * 32 + quad * 8];
            #pragma unroll
            for (int mi = 0; mi < 2; mi++) {
                if (mi == 1 && !sact) continue;
                #pragma unroll
                for (int nk = 0; nk < 4; nk++)
                    st[mi][nk] = __builtin_amdgcn_mfma_f32_16x16x32_bf16(
                        ak[nk], bq[mi][ks], st[mi][nk], 0, 0, 0);
            }
        }

        #pragma unroll
        for (int mi = 0; mi < 2; mi++) {
            if (mi == 1 && !sact) continue;
            const bool diag = (mi == 0) ? (t == nt - 1) : (t == p);
            const int qrow = ((mi == 0) ? rowbase0 : rowbase1) + l16;
            #pragma unroll
            for (int nk = 0; nk < 4; nk++) {
                const int kc0 = j0 + nk * 16 + quad * 4;
                float pv[4];
                #pragma unroll
                for (int r = 0; r < 4; r++) {
                    float e = __expf(st[mi][nk][r]);
                    pv[r] = (diag && (kc0 + r > qrow)) ? 0.f : e;
                }
                uint2 w2 = make_uint2(pk_bf16(pv[0], pv[1]), pk_bf16(pv[2], pv[3]));
                *(uint2*)&Pl[wave][mi * 16 + l16][nk * 16 + quad * 4] = w2;
            }
        }

        #pragma unroll
        for (int ksp = 0; ksp < 2; ksp++) {
            bf16x8 bv[4];
            #pragma unroll
            for (int nd = 0; nd < 4; nd++) {
                const int d = nd * 16 + l16;
                bv[nd] = *(const bf16x8*)&Vt[cur][d][(ksp * 32 + quad * 8 + 8 * (d >> 3)) & 63];
            }
            #pragma unroll
            for (int mi = 0; mi < 2; mi++) {
                if (mi == 1 && !sact) continue;
                bf16x8 ap = *(const bf16x8*)&Pl[wave][mi * 16 + l16][ksp * 32 + quad * 8];
                acc_l[mi] = __builtin_amdgcn_mfma_f32_16x16x32_bf16(
                    ap, ones, acc_l[mi], 0, 0, 0);
                #pragma unroll
                for (int nd = 0; nd < 4; nd++)
                    acc_o[mi][nd] = __builtin_amdgcn_mfma_f32_16x16x32_bf16(
                        ap, bv[nd], acc_o[mi][nd], 0, 0, 0);
            }
        }

        if (hasNext) {
            *(uint4*)&Ks[nxt][sr][sc]     = ka;
            *(uint4*)&Ks[nxt][sr][sc + 8] = kb;
            ushort_t tmp[16];
            *(uint4*)&tmp[0] = va;
            *(uint4*)&tmp[8] = vb;
            #pragma unroll
            for (int e = 0; e < 16; e++) {
                int d = sc + e;
                Vt[nxt][d][(sr + 8 * (d >> 3)) & 63] = tmp[e];
            }
        }
        __syncthreads();
    }

    #pragma unroll
    for (int mi = 0; mi < 2; mi++) {
        const int rb = (mi == 0) ? rowbase0 : rowbase1;
        float inv[4];
        #pragma unroll
        for (int r = 0; r < 4; r++) inv[r] = 1.0f / acc_l[mi][r];
        #pragma unroll
        for (int nd = 0; nd < 4; nd++)
            #pragma unroll
            for (int r = 0; r < 4; r++) {
                int row = rb + quad * 4 + r;
                int col = h * HD + nd * 16 + l16;
                O[(size_t)row * (NQH * HD) + col] = f2bf(acc_o[mi][nd][r] * inv[r]);
            }
    }
}

// ---------------------------------------------------------------------------
// attn_v8: best-measured attn variant (44.0 us, round 2). 256-thread /
// 4-wave blocks owning 64 contiguous q-rows; grid = 32 heads x 32 strips =
// 1024 blocks; LDS 41 KB -> 3 blocks/CU resident. Every wave's diagonal
// tile is the LAST tile -> all 4 waves active on all nt = qi+1 iterations.
// Dispatch order: qi = bz<16 ? 31-bz : bz-16 (heaviest first). K from qkv,
// V^T from VtG, both DMA'd (global_load_lds w16) with the XOR source
// swizzle; double-buffered; one barrier per tile. [v9 (lane-local PV) and
// v10 (KV-split) both measured worse: 45.8 / 47.8 -> reverted.]
// ---------------------------------------------------------------------------
__global__ __launch_bounds__(256, 3) void attn_v8(
    const ushort_t* __restrict__ qkv, const ushort_t* __restrict__ VtG,
    ushort_t* __restrict__ O) {
    const int bx   = blockIdx.x;            // 1024 blocks
    const int h    = bx & 31;
    const int bz   = bx >> 5;               // 0..31
    const int qi   = (bz < 16) ? (31 - bz) : (bz - 16);
    const int kvh  = h >> 2;
    const int q0   = qi * 64;
    const int tid  = threadIdx.x;
    const int wave = tid >> 6;              // 0..3
    const int lane = tid & 63;
    const int quad = lane >> 4;
    const int l16  = lane & 15;

    __shared__ __align__(16) ushort_t Ks[2][64][64];   // 16 KB (DMA, swizzled)
    __shared__ __align__(16) ushort_t Vt[2][64][64];   // 16 KB (DMA, swizzled)
    __shared__ __align__(16) ushort_t Pl[4][16][72];   // 9 KB

    const int rb = q0 + wave * 16;          // this wave's 16 q-rows
    const int nt = qi + 1;                  // diag tile == last tile, all waves

    // Q B-frags (lane l16 = qrow), pre-scaled by (1/8)*log2(e) for exp2
    bf16x8 bq[2];
    #pragma unroll
    for (int ks = 0; ks < 2; ks++) {
        uint4 u = *(const uint4*)&qkv[(size_t)(rb + l16) * QKV_O
                                      + h * HD + ks * 32 + quad * 8];
        float f[8]; unpack8(f, u);
        const float QS = 0.18033688011112042f;   // 0.125 * log2(e)
        uint4 w = make_uint4(
            pk_bf16(f[0] * QS, f[1] * QS), pk_bf16(f[2] * QS, f[3] * QS),
            pk_bf16(f[4] * QS, f[5] * QS), pk_bf16(f[6] * QS, f[7] * QS));
        __builtin_memcpy(&bq[ks], &w, 16);
    }

    bf16x8 ones;
    #pragma unroll
    for (int e = 0; e < 8; e++) ones[e] = (__bf16)1.0f;

    f32x4 acc_o[4];
    f32x4 acc_l;
    {
        f32x4 z = {0.f, 0.f, 0.f, 0.f};
        acc_l = z;
        #pragma unroll
        for (int n = 0; n < 4; n++) acc_o[n] = z;
    }

    // DMA lane geometry (XOR swizzle on the source side); wave stages 16 rows
    // of K and 16 rows of V^T per tile (2 x 1KB DMA ops each).
    const int lr = lane >> 3;                 // row-in-group 0..7
    const int cg = ((lane & 7) ^ lr) << 3;    // swizzled global chunk (elems)
    const ushort_t* kbase = &qkv[(size_t)(wave * 16 + lr) * QKV_O + K_COL + kvh * HD + cg];
    const size_t    kr8   = (size_t)8 * QKV_O;
    const ushort_t* vbase = &VtG[(size_t)(kvh * HD + wave * 16 + lr) * S_LEN + cg];
    const size_t    vr8   = (size_t)8 * S_LEN;

    // ---- prologue: DMA tile 0 -> buffer 0 ----
    __builtin_amdgcn_global_load_lds(GLB(kbase),       LDSP(&Ks[0][wave * 16][0]),     16, 0, 0);
    __builtin_amdgcn_global_load_lds(GLB(kbase + kr8), LDSP(&Ks[0][wave * 16 + 8][0]), 16, 0, 0);
    __builtin_amdgcn_global_load_lds(GLB(vbase),       LDSP(&Vt[0][wave * 16][0]),     16, 0, 0);
    __builtin_amdgcn_global_load_lds(GLB(vbase + vr8), LDSP(&Vt[0][wave * 16 + 8][0]), 16, 0, 0);
    __syncthreads();

    for (int t = 0; t < nt; t++) {
        const int cur = t & 1, nxt = cur ^ 1;
        const int j0 = t * 64;

        // ---- DMA-prefetch tile t+1 -> alternate buffer (flies during compute)
        if (t + 1 < nt) {
            const size_t kj = (size_t)(j0 + 64) * QKV_O;
            __builtin_amdgcn_global_load_lds(GLB(kbase + kj),             LDSP(&Ks[nxt][wave * 16][0]),     16, 0, 0);
            __builtin_amdgcn_global_load_lds(GLB(kbase + kj + kr8),       LDSP(&Ks[nxt][wave * 16 + 8][0]), 16, 0, 0);
            __builtin_amdgcn_global_load_lds(GLB(vbase + (j0 + 64)),      LDSP(&Vt[nxt][wave * 16][0]),     16, 0, 0);
            __builtin_amdgcn_global_load_lds(GLB(vbase + (j0 + 64) + vr8),LDSP(&Vt[nxt][wave * 16 + 8][0]), 16, 0, 0);
        }

        // ---- S^T = K·Q^T ----
        f32x4 st[4];
        #pragma unroll
        for (int nk = 0; nk < 4; nk++) {
            f32x4 z = {0.f, 0.f, 0.f, 0.f};
            st[nk] = z;
        }
        #pragma unroll
        for (int ks = 0; ks < 2; ks++) {
            const int ca = (((ks << 2) + quad) ^ (l16 & 7)) << 3;
            bf16x8 ak[4];
            #pragma unroll
            for (int nk = 0; nk < 4; nk++)
                ak[nk] = *(const bf16x8*)&Ks[cur][nk * 16 + l16][ca];
            #pragma unroll
            for (int nk = 0; nk < 4; nk++)
                st[nk] = __builtin_amdgcn_mfma_f32_16x16x32_bf16(
                    ak[nk], bq[ks], st[nk], 0, 0, 0);
        }

        // ---- exp2 + causal mask (diag = last tile only), b64 P stores ----
        if (t == nt - 1) {
            const int qrow = rb + l16;
            #pragma unroll
            for (int nk = 0; nk < 4; nk++) {
                const int kc0 = j0 + nk * 16 + quad * 4;
                float pv[4];
                #pragma unroll
                for (int r = 0; r < 4; r++)
                    pv[r] = (kc0 + r > qrow) ? 0.f : exp2f(st[nk][r]);
                uint2 w2 = make_uint2(pk_bf16(pv[0], pv[1]), pk_bf16(pv[2], pv[3]));
                *(uint2*)&Pl[wave][l16][nk * 16 + quad * 4] = w2;
            }
        } else {
            #pragma unroll
            for (int nk = 0; nk < 4; nk++) {
                float pv[4];
                #pragma unroll
                for (int r = 0; r < 4; r++)
                    pv[r] = exp2f(st[nk][r]);
                uint2 w2 = make_uint2(pk_bf16(pv[0], pv[1]), pk_bf16(pv[2], pv[3]));
                *(uint2*)&Pl[wave][l16][nk * 16 + quad * 4] = w2;
            }
        }

        // ---- l += P·1 ; O += P·V ----
        #pragma unroll
        for (int ksp = 0; ksp < 2; ksp++) {
            const int ca = (((ksp << 2) + quad) ^ (l16 & 7)) << 3;
            bf16x8 bv[4];
            #pragma unroll
            for (int nd = 0; nd < 4; nd++)
                bv[nd] = *(const bf16x8*)&Vt[cur][nd * 16 + l16][ca];
            bf16x8 ap = *(const bf16x8*)&Pl[wave][l16][ksp * 32 + quad * 8];
            acc_l = __builtin_amdgcn_mfma_f32_16x16x32_bf16(
                ap, ones, acc_l, 0, 0, 0);
            #pragma unroll
            for (int nd = 0; nd < 4; nd++)
                acc_o[nd] = __builtin_amdgcn_mfma_f32_16x16x32_bf16(
                    ap, bv[nd], acc_o[nd], 0, 0, 0);
        }
        __syncthreads();   // one barrier/tile; compiler drains vmcnt here
    }

    // ---- epilogue: O / l ----
    float inv[4];
    #pragma unroll
    for (int r = 0; r < 4; r++) inv[r] = 1.0f / acc_l[r];
    #pragma unroll
    for (int nd = 0; nd < 4; nd++)
        #pragma unroll
        for (int r = 0; r < 4; r++) {
            int row = rb + quad * 4 + r;
            int col = h * HD + nd * 16 + l16;
            O[(size_t)row * (NQH * HD) + col] = f2bf(acc_o[nd][r] * inv[r]);
        }
}

// ---------------------------------------------------------------------------
extern "C" void kernel_launch(void* const* d_in, const int* in_sizes, int n_in,
                              void* d_out, int out_size, void* d_ws, size_t ws_size,
                              hipStream_t stream) {
    const float* x     = (const float*)d_in[0];  // [2048][2048] fp32
    const float* cosp  = (const float*)d_in[1];  // [2048][64]   fp32
    const float* sinp  = (const float*)d_in[2];  // [2048][64]   fp32
    const float* w_qkv = (const float*)d_in[3];  // [3072][2048] fp32
    const float* w_out = (const float*)d_in[4];  // [2048][2048] fp32
    float* out = (float*)d_out;                  // [2048][2048] fp32

    const size_t NQKV = (size_t)S_LEN * QKV_O;   // 6291456
    const size_t NH2  = (size_t)S_LEN * HID;     // 4194304
    const size_t NVT  = (size_t)(NKVH * HD) * S_LEN;  // 1048576
    const size_t need_old = 2 * (NQKV + NH2) * sizeof(ushort_t);        // 41.9 MB
    const size_t need_new = need_old + NVT * sizeof(ushort_t);          // 44.0 MB

    ushort_t* qkv = (ushort_t*)d_ws;             // bf16 [2048][3072]
    ushort_t* x_bf    = qkv + NQKV;
    ushort_t* attnO   = x_bf;                    // disjoint lifetimes
    ushort_t* wqkv_bf = x_bf + NH2;
    ushort_t* wout_bf = wqkv_bf + NQKV;
    ushort_t* VtG     = wout_bf + NH2;           // bf16 [512][2048]

    if (ws_size >= need_new) {
        convert3<<<XN8 / 256 + QN8 / 256 + ON8 / 256, 256, 0, stream>>>(
            x, w_qkv, w_out, x_bf, wqkv_bf, wout_bf);

        // 1) qkv(q,k w/ RoPE) + VtG(V^T) = x @ w_qkv^T  (128x128 tiles)
        dim3 g1(QKV_O / 128, S_LEN / 128);
        gemm128<false, true, true><<<g1, 256, 0, stream>>>(
            x_bf, wqkv_bf, qkv, S_LEN, QKV_O, HID, cosp, sinp, VtG);

        // 2) causal GQA attention (best-measured v8)
        attn_v8<<<32 * NQH, 256, 0, stream>>>(qkv, VtG, attnO);

        // 3) out = attnO @ w_out^T  (128x128 tiles, 256-block grid = 1/CU)
        dim3 g2(HID / 128, S_LEN / 128);
        gemm128<true, false, false><<<g2, 256, 0, stream>>>(
            attnO, wout_bf, out, S_LEN, HID, HID, nullptr, nullptr, nullptr);
    } else if (ws_size >= need_old) {
        // round-13 path (no VtG room)
        convert3<<<XN8 / 256 + QN8 / 256 + ON8 / 256, 256, 0, stream>>>(
            x, w_qkv, w_out, x_bf, wqkv_bf, wout_bf);

        dim3 g1(QKV_O / 128, S_LEN / 128);
        gemm128<false, true, false><<<g1, 256, 0, stream>>>(
            x_bf, wqkv_bf, qkv, S_LEN, QKV_O, HID, cosp, sinp, nullptr);

        attn_v5<<<16 * NQH, 256, 0, stream>>>(qkv, attnO);

        dim3 g2(HID / 128, S_LEN / 128);
        gemm128<true, false, false><<<g2, 256, 0, stream>>>(
            attnO, wout_bf, out, S_LEN, HID, HID, nullptr, nullptr, nullptr);
    } else {
        ushort_t* attnO2 = qkv + NQKV;

        dim3 g1(QKV_O / 128, S_LEN / 128);
        gemm_bt<true, true, false><<<g1, 256, 0, stream>>>(x, w_qkv, qkv, S_LEN, QKV_O, HID);

        int rope_threads = S_LEN * (NQH + NKVH);
        rope_kernel<<<(rope_threads + 255) / 256, 256, 0, stream>>>(qkv, cosp, sinp);

        attn_v5<<<16 * NQH, 256, 0, stream>>>(qkv, attnO2);

        dim3 g2(HID / 128, S_LEN / 128);
        gemm_bt<false, true, true><<<g2, 256, 0, stream>>>(attnO2, w_out, out, S_LEN, HID, HID);
    }
}

// Round 6
// 201.416 us; speedup vs baseline: 1.0895x; 1.0895x over previous
//
#include <hip/hip_runtime.h>
#include <hip/hip_bf16.h>
#include <stdint.h>

// Problem constants (B=1). I/O dtype: fp32. Internals bf16 (MFMA path).
#define S_LEN 2048
#define HID   2048
#define NQH   32
#define NKVH  8
#define HD    64
#define QKV_O 3072      // (32 + 2*8) * 64
#define K_COL 2048      // col offset of K block in qkv row
#define V_COL 2560      // col offset of V block in qkv row

typedef unsigned short ushort_t;
typedef __bf16 bf16x8 __attribute__((ext_vector_type(8)));
typedef float  f32x4  __attribute__((ext_vector_type(4)));

#define GLB(p) ((const __attribute__((address_space(1))) void*)(p))
#define LDSP(p) ((__attribute__((address_space(3))) void*)(p))

__device__ __forceinline__ ushort_t f2bf(float f) {
    unsigned int x = __float_as_uint(f);
    unsigned int r = (x + 0x7fffu + ((x >> 16) & 1u)) >> 16;   // RNE
    return (ushort_t)r;
}
__device__ __forceinline__ unsigned int pk_bf16(float a, float b) {
    __hip_bfloat162 h = __float22bfloat162_rn(make_float2(a, b));
    unsigned int r;
    __builtin_memcpy(&r, &h, 4);
    return r;
}
__device__ __forceinline__ void unpack8(float* dst, uint4 u) {
    dst[0] = __uint_as_float(u.x << 16); dst[1] = __uint_as_float(u.x & 0xffff0000u);
    dst[2] = __uint_as_float(u.y << 16); dst[3] = __uint_as_float(u.y & 0xffff0000u);
    dst[4] = __uint_as_float(u.z << 16); dst[5] = __uint_as_float(u.z & 0xffff0000u);
    dst[6] = __uint_as_float(u.w << 16); dst[7] = __uint_as_float(u.w & 0xffff0000u);
}

// ---------------------------------------------------------------------------
// convert3: fp32 -> bf16 for x, w_qkv, w_out (unchanged)
// ---------------------------------------------------------------------------
#define XN8 (S_LEN * HID / 8)          // 524288
#define QN8 (QKV_O * HID / 8)          // 786432
#define ON8 (HID * HID / 8)            // 524288

__global__ __launch_bounds__(256) void convert3(
    const float* __restrict__ x, const float* __restrict__ wq,
    const float* __restrict__ wo, ushort_t* __restrict__ xb,
    ushort_t* __restrict__ wqb, ushort_t* __restrict__ wob) {
    int i = blockIdx.x * 256 + threadIdx.x;
    const float* s; ushort_t* d; int off;
    if (i < XN8)            { s = x;  d = xb;  off = i; }
    else if (i < XN8 + QN8) { s = wq; d = wqb; off = i - XN8; }
    else                    { s = wo; d = wob; off = i - XN8 - QN8; }
    const float4* sp = (const float4*)s + (size_t)off * 2;
    float4 a = sp[0], b = sp[1];
    *(uint4*)(d + (size_t)off * 8) = make_uint4(
        pk_bf16(a.x, a.y), pk_bf16(a.z, a.w),
        pk_bf16(b.x, b.y), pk_bf16(b.z, b.w));
}

// ---------------------------------------------------------------------------
// gemm_bk64: pure-bf16 GEMM, 64x128 tile, BK=64, XOR-swizzled LDS,
// DOUBLE-BUFFERED (round-6): prologue stages k=0; each iteration issues the
// k+1 DMA into the alternate buffer BEFORE computing k, then one barrier.
// vs round-2 (two barriers per k-step, DMA latency fully exposed between
// them): the ~200-900cy global_load_lds latency now hides under the 16
// MFMA + 8 ds_read of the current tile. Numerics identical.
// Round-5 lesson: 128^2 tile shrank the grid to 1-1.5 blocks/CU (Occ 14%,
// gemm1 49us) — at this problem size grid residency (3/2 blocks/CU here)
// dominates per-block efficiency, so the 64x128 shape stays.
// ROPE: fused in-lane RoPE epilogue for q/k tiles (bn < V_COL).
// VT:   V tiles (bn >= V_COL) stored transposed to VtG[vcol][seq].
// ---------------------------------------------------------------------------
template<bool CF32, bool ROPE, bool VT>
__global__ __launch_bounds__(256, 3) void gemm_bk64(
    const ushort_t* __restrict__ A, const ushort_t* __restrict__ Bt,
    void* __restrict__ Cp, int M, int N, int K,
    const float* __restrict__ cs, const float* __restrict__ sn,
    ushort_t* __restrict__ VtG) {
    __shared__ ushort_t As[2][64][64];     // 16 KB
    __shared__ ushort_t Bs[2][128][64];    // 32 KB

    const int t    = threadIdx.x;
    const int wave = t >> 6;
    const int lane = t & 63;
    const int quad = lane >> 4;
    const int l16  = lane & 15;
    const int wm   = (wave >> 1) << 5;
    const int wn   = (wave & 1)  << 6;
    const int bm   = blockIdx.y * 64;
    const int bn   = blockIdx.x * 128;
    const int lr   = lane >> 3;
    const int lc   = ((lane & 7) ^ lr) << 3;

    f32x4 acc[2][4];
    #pragma unroll
    for (int i = 0; i < 2; i++)
        #pragma unroll
        for (int j = 0; j < 4; j++) {
            f32x4 z = {0.f, 0.f, 0.f, 0.f};
            acc[i][j] = z;
        }

    const ushort_t* a0 = &A[(size_t)(bm + wave * 16 + lr) * K + lc];
    const ushort_t* b0 = &Bt[(size_t)(bn + wave * 32 + lr) * K + lc];
    const size_t r8 = (size_t)8 * K;

    // ---- prologue: stage k=0 into buffer 0 ----
    __builtin_amdgcn_global_load_lds(GLB(a0),          LDSP(&As[0][wave * 16][0]),      16, 0, 0);
    __builtin_amdgcn_global_load_lds(GLB(a0 + r8),     LDSP(&As[0][wave * 16 + 8][0]),  16, 0, 0);
    __builtin_amdgcn_global_load_lds(GLB(b0),          LDSP(&Bs[0][wave * 32][0]),      16, 0, 0);
    __builtin_amdgcn_global_load_lds(GLB(b0 + r8),     LDSP(&Bs[0][wave * 32 + 8][0]),  16, 0, 0);
    __builtin_amdgcn_global_load_lds(GLB(b0 + 2 * r8), LDSP(&Bs[0][wave * 32 + 16][0]), 16, 0, 0);
    __builtin_amdgcn_global_load_lds(GLB(b0 + 3 * r8), LDSP(&Bs[0][wave * 32 + 24][0]), 16, 0, 0);
    __syncthreads();

    const int nk = K >> 6;
    for (int kk = 0; kk < nk; kk++) {
        const int cur = kk & 1, nxt = cur ^ 1;

        // ---- issue DMA for k+1 into the alternate buffer (flies under MFMA)
        if (kk + 1 < nk) {
            const int k0 = (kk + 1) << 6;
            __builtin_amdgcn_global_load_lds(GLB(a0 + k0),          LDSP(&As[nxt][wave * 16][0]),      16, 0, 0);
            __builtin_amdgcn_global_load_lds(GLB(a0 + k0 + r8),     LDSP(&As[nxt][wave * 16 + 8][0]),  16, 0, 0);
            __builtin_amdgcn_global_load_lds(GLB(b0 + k0),          LDSP(&Bs[nxt][wave * 32][0]),      16, 0, 0);
            __builtin_amdgcn_global_load_lds(GLB(b0 + k0 + r8),     LDSP(&Bs[nxt][wave * 32 + 8][0]),  16, 0, 0);
            __builtin_amdgcn_global_load_lds(GLB(b0 + k0 + 2 * r8), LDSP(&Bs[nxt][wave * 32 + 16][0]), 16, 0, 0);
            __builtin_amdgcn_global_load_lds(GLB(b0 + k0 + 3 * r8), LDSP(&Bs[nxt][wave * 32 + 24][0]), 16, 0, 0);
        }

        // ---- compute current buffer ----
        #pragma unroll
        for (int ks = 0; ks < 2; ks++) {
            const int ca = (((ks << 2) + quad) ^ (l16 & 7)) << 3;
            bf16x8 af[2], bfr[4];
            #pragma unroll
            for (int i = 0; i < 2; i++)
                af[i] = *(const bf16x8*)&As[cur][wm + i * 16 + l16][ca];
            #pragma unroll
            for (int j = 0; j < 4; j++)
                bfr[j] = *(const bf16x8*)&Bs[cur][wn + j * 16 + l16][ca];

            #pragma unroll
            for (int i = 0; i < 2; i++)
                #pragma unroll
                for (int j = 0; j < 4; j++)
                    acc[i][j] = __builtin_amdgcn_mfma_f32_16x16x32_bf16(
                        af[i], bfr[j], acc[i][j], 0, 0, 0);
        }
        __syncthreads();   // one barrier/k-step; drains vmcnt -> buf[nxt] ready
    }

    // Epilogue: C/D layout col=lane&15 (+nd*16), row=quad*4+reg
    if (ROPE && bn < V_COL) {
        #pragma unroll
        for (int i = 0; i < 2; i++)
            #pragma unroll
            for (int r = 0; r < 4; r++) {
                const int srow = bm + wm + i * 16 + quad * 4 + r;
                float cv[4], sv[4], o[4];
                #pragma unroll
                for (int nd = 0; nd < 4; nd++) {
                    const int d = nd * 16 + l16;
                    cv[nd] = cs[srow * HD + d];
                    sv[nd] = sn[srow * HD + d];
                }
                o[0] = acc[i][0][r] * cv[0] - acc[i][2][r] * sv[0];
                o[1] = acc[i][1][r] * cv[1] - acc[i][3][r] * sv[1];
                o[2] = acc[i][2][r] * cv[2] + acc[i][0][r] * sv[2];
                o[3] = acc[i][3][r] * cv[3] + acc[i][1][r] * sv[3];
                #pragma unroll
                for (int nd = 0; nd < 4; nd++) {
                    const int col = bn + wn + nd * 16 + l16;
                    ((ushort_t*)Cp)[(size_t)srow * N + col] = f2bf(o[nd]);
                }
            }
    } else if (VT && bn >= V_COL) {
        #pragma unroll
        for (int i = 0; i < 2; i++) {
            const int srow0 = bm + wm + i * 16 + quad * 4;
            #pragma unroll
            for (int nd = 0; nd < 4; nd++) {
                const int vcol = bn + wn + nd * 16 + l16 - V_COL;
                uint2 w2 = make_uint2(
                    pk_bf16(acc[i][nd][0], acc[i][nd][1]),
                    pk_bf16(acc[i][nd][2], acc[i][nd][3]));
                *(uint2*)&VtG[(size_t)vcol * S_LEN + srow0] = w2;
            }
        }
    } else {
        #pragma unroll
        for (int i = 0; i < 2; i++)
            #pragma unroll
            for (int j = 0; j < 4; j++)
                #pragma unroll
                for (int r = 0; r < 4; r++) {
                    int row = bm + wm + i * 16 + quad * 4 + r;
                    int col = bn + wn + j * 16 + l16;
                    if (CF32)
                        ((float*)Cp)[(size_t)row * N + col] = acc[i][j][r];
                    else
                        ((ushort_t*)Cp)[(size_t)row * N + col] = f2bf(acc[i][j][r]);
                }
    }
}

// ---------------------------------------------------------------------------
// Fallback GEMM with fused fp32->bf16 staging (small-ws path; unchanged)
// ---------------------------------------------------------------------------
template<bool AF32, bool BF32, bool CF32>
__global__ __launch_bounds__(256) void gemm_bt(
    const void* __restrict__ Ap, const void* __restrict__ Bp,
    void* __restrict__ Cp, int M, int N, int K) {
    __shared__ ushort_t As[128][40];
    __shared__ ushort_t Bs[128][40];

    const int t    = threadIdx.x;
    const int wave = t >> 6;
    const int lane = t & 63;
    const int quad = lane >> 4;
    const int l16  = lane & 15;
    const int wm   = (wave >> 1) << 6;
    const int wn   = (wave & 1)  << 6;
    const int bm   = blockIdx.y * 128;
    const int bn   = blockIdx.x * 128;
    const int sr   = t >> 2;
    const int sc   = (t & 3) << 3;

    f32x4 acc[4][4];
    #pragma unroll
    for (int i = 0; i < 4; i++)
        #pragma unroll
        for (int j = 0; j < 4; j++) {
            f32x4 z = {0.f, 0.f, 0.f, 0.f};
            acc[i][j] = z;
        }

    for (int k0 = 0; k0 < K; k0 += 32) {
        __syncthreads();
        if (AF32) {
            const float* A = (const float*)Ap;
            const float* p0 = &A[(size_t)(bm + sr) * K + k0 + sc];
            const float* p1 = &A[(size_t)(bm + sr + 64) * K + k0 + sc];
            float4 a0 = *(const float4*)p0, a1 = *(const float4*)(p0 + 4);
            float4 b0 = *(const float4*)p1, b1 = *(const float4*)(p1 + 4);
            *(uint4*)&As[sr][sc] = make_uint4(
                pk_bf16(a0.x, a0.y), pk_bf16(a0.z, a0.w),
                pk_bf16(a1.x, a1.y), pk_bf16(a1.z, a1.w));
            *(uint4*)&As[sr + 64][sc] = make_uint4(
                pk_bf16(b0.x, b0.y), pk_bf16(b0.z, b0.w),
                pk_bf16(b1.x, b1.y), pk_bf16(b1.z, b1.w));
        } else {
            const ushort_t* A = (const ushort_t*)Ap;
            *(uint4*)&As[sr][sc]      = *(const uint4*)&A[(size_t)(bm + sr) * K + k0 + sc];
            *(uint4*)&As[sr + 64][sc] = *(const uint4*)&A[(size_t)(bm + sr + 64) * K + k0 + sc];
        }
        if (BF32) {
            const float* B = (const float*)Bp;
            const float* p0 = &B[(size_t)(bn + sr) * K + k0 + sc];
            const float* p1 = &B[(size_t)(bn + sr + 64) * K + k0 + sc];
            float4 a0 = *(const float4*)p0, a1 = *(const float4*)(p0 + 4);
            float4 b0 = *(const float4*)p1, b1 = *(const float4*)(p1 + 4);
            *(uint4*)&Bs[sr][sc] = make_uint4(
                pk_bf16(a0.x, a0.y), pk_bf16(a0.z, a0.w),
                pk_bf16(a1.x, a1.y), pk_bf16(a1.z, a1.w));
            *(uint4*)&Bs[sr + 64][sc] = make_uint4(
                pk_bf16(b0.x, b0.y), pk_bf16(b0.z, b0.w),
                pk_bf16(b1.x, b1.y), pk_bf16(b1.z, b1.w));
        } else {
            const ushort_t* B = (const ushort_t*)Bp;
            *(uint4*)&Bs[sr][sc]      = *(const uint4*)&B[(size_t)(bn + sr) * K + k0 + sc];
            *(uint4*)&Bs[sr + 64][sc] = *(const uint4*)&B[(size_t)(bn + sr + 64) * K + k0 + sc];
        }
        __syncthreads();

        bf16x8 af[4], bfr[4];
        #pragma unroll
        for (int i = 0; i < 4; i++)
            af[i] = *(const bf16x8*)&As[wm + i * 16 + l16][quad * 8];
        #pragma unroll
        for (int j = 0; j < 4; j++)
            bfr[j] = *(const bf16x8*)&Bs[wn + j * 16 + l16][quad * 8];

        #pragma unroll
        for (int i = 0; i < 4; i++)
            #pragma unroll
            for (int j = 0; j < 4; j++)
                acc[i][j] = __builtin_amdgcn_mfma_f32_16x16x32_bf16(
                    af[i], bfr[j], acc[i][j], 0, 0, 0);
    }

    #pragma unroll
    for (int i = 0; i < 4; i++)
        #pragma unroll
        for (int j = 0; j < 4; j++)
            #pragma unroll
            for (int r = 0; r < 4; r++) {
                int row = bm + wm + i * 16 + quad * 4 + r;
                int col = bn + wn + j * 16 + l16;
                if (CF32)
                    ((float*)Cp)[(size_t)row * N + col] = acc[i][j][r];
                else
                    ((ushort_t*)Cp)[(size_t)row * N + col] = f2bf(acc[i][j][r]);
            }
}

// ---------------------------------------------------------------------------
// RoPE standalone (fallback path only)
// ---------------------------------------------------------------------------
__global__ __launch_bounds__(256) void rope_kernel(
    ushort_t* __restrict__ qkv, const float* __restrict__ cs,
    const float* __restrict__ sn) {
    int idx = blockIdx.x * 256 + threadIdx.x;
    if (idx >= S_LEN * (NQH + NKVH)) return;
    int s  = idx / (NQH + NKVH);
    int hh = idx - s * (NQH + NKVH);

    ushort_t* p = &qkv[(size_t)s * QKV_O + hh * HD];
    const uint4* p4 = (const uint4*)p;
    float v[HD], c[HD], sv[HD];
    #pragma unroll
    for (int b = 0; b < 8; b++) unpack8(&v[b * 8], p4[b]);
    const float4* c4 = (const float4*)&cs[s * HD];
    const float4* s4 = (const float4*)&sn[s * HD];
    #pragma unroll
    for (int b = 0; b < 16; b++) {
        ((float4*)c)[b]  = c4[b];
        ((float4*)sv)[b] = s4[b];
    }
    float o[HD];
    #pragma unroll
    for (int d = 0; d < 32; d++) {
        o[d]      = v[d] * c[d]           - v[d + 32] * sv[d];
        o[d + 32] = v[d + 32] * c[d + 32] + v[d]      * sv[d + 32];
    }
    unsigned int* pw = (unsigned int*)p;
    #pragma unroll
    for (int d = 0; d < HD; d += 2)
        pw[d >> 1] = pk_bf16(o[d], o[d + 1]);
}

// ---------------------------------------------------------------------------
// attn_v5: round-12/13 kernel (fallback paths; reads V from qkv)
// ---------------------------------------------------------------------------
__global__ __launch_bounds__(256) void attn_v5(
    const ushort_t* __restrict__ qkv, ushort_t* __restrict__ O) {
    const int bx   = blockIdx.x;
    const int h    = bx & 31;
    const int p    = bx >> 5;
    const int kvh  = h >> 2;
    const int q0d  = (31 - p) * 64;
    const int q0s  = p * 64;
    const int tid  = threadIdx.x;
    const int wave = tid >> 6;
    const int lane = tid & 63;
    const int quad = lane >> 4;
    const int l16  = lane & 15;

    __shared__ __align__(16) ushort_t Ks[2][64][72];
    __shared__ __align__(16) ushort_t Vt[2][64][72];
    __shared__ __align__(16) ushort_t Pl[4][32][72];

    const int rowbase0 = q0d + wave * 16;
    const int rowbase1 = q0s + wave * 16;

    bf16x8 bq[2][2];
    #pragma unroll
    for (int mi = 0; mi < 2; mi++) {
        const int rb = (mi == 0) ? rowbase0 : rowbase1;
        #pragma unroll
        for (int ks = 0; ks < 2; ks++) {
            uint4 u = *(const uint4*)&qkv[(size_t)(rb + l16) * QKV_O
                                          + h * HD + ks * 32 + quad * 8];
            float f[8]; unpack8(f, u);
            uint4 w = make_uint4(
                pk_bf16(f[0] * 0.125f, f[1] * 0.125f),
                pk_bf16(f[2] * 0.125f, f[3] * 0.125f),
                pk_bf16(f[4] * 0.125f, f[5] * 0.125f),
                pk_bf16(f[6] * 0.125f, f[7] * 0.125f));
            __builtin_memcpy(&bq[mi][ks], &w, 16);
        }
    }

    bf16x8 ones;
    #pragma unroll
    for (int e = 0; e < 8; e++) ones[e] = (__bf16)1.0f;

    f32x4 acc_o[2][4];
    f32x4 acc_l[2];
    #pragma unroll
    for (int mi = 0; mi < 2; mi++) {
        f32x4 z = {0.f, 0.f, 0.f, 0.f};
        acc_l[mi] = z;
        #pragma unroll
        for (int n = 0; n < 4; n++) acc_o[mi][n] = z;
    }

    const int nt = 32 - p;
    const int sr = tid >> 2;
    const int sc = (tid & 3) << 4;

    {
        const ushort_t* kp = &qkv[(size_t)sr * QKV_O + K_COL + kvh * HD + sc];
        *(uint4*)&Ks[0][sr][sc]     = *(const uint4*)kp;
        *(uint4*)&Ks[0][sr][sc + 8] = *(const uint4*)(kp + 8);
        const ushort_t* vp = &qkv[(size_t)sr * QKV_O + V_COL + kvh * HD + sc];
        ushort_t tmp[16];
        *(uint4*)&tmp[0] = *(const uint4*)vp;
        *(uint4*)&tmp[8] = *(const uint4*)(vp + 8);
        #pragma unroll
        for (int e = 0; e < 16; e++) {
            int d = sc + e;
            Vt[0][d][(sr + 8 * (d >> 3)) & 63] = tmp[e];
        }
    }
    __syncthreads();

    for (int t = 0; t < nt; t++) {
        const int cur = t & 1, nxt = cur ^ 1;
        const int j0 = t * 64;
        const bool hasNext = (t + 1 < nt);

        uint4 ka, kb, va, vb;
        if (hasNext) {
            const size_t rbase = (size_t)(j0 + 64 + sr) * QKV_O;
            const ushort_t* kp = &qkv[rbase + K_COL + kvh * HD + sc];
            ka = *(const uint4*)kp; kb = *(const uint4*)(kp + 8);
            const ushort_t* vp = &qkv[rbase + V_COL + kvh * HD + sc];
            va = *(const uint4*)vp; vb = *(const uint4*)(vp + 8);
        }

        const bool sact = (t <= p);

        f32x4 st[2][4];
        #pragma unroll
        for (int mi = 0; mi < 2; mi++)
            #pragma unroll
            for (int nk = 0; nk < 4; nk++) {
                f32x4 z = {0.f, 0.f, 0.f, 0.f};
                st[mi][nk] = z;
            }
        #pragma unroll
        for (int ks = 0; ks < 2; ks++) {
            bf16x8 ak[4];
            #pragma unroll
            for (int nk = 0; nk < 4; nk++)
                ak[nk] = *(const bf16x8*)&Ks[cur][nk * 16 + l16][ks * 32 + quad * 8];
            #pragma unroll
            for (int mi = 0; mi < 2; mi++) {
                if (mi == 1 && !sact) continue;
                #pragma unroll
                for (int nk = 0; nk < 4; nk++)
                    st[mi][nk] = __builtin_amdgcn_mfma_f32_16x16x32_bf16(
                        ak[nk], bq[mi][ks], st[mi][nk], 0, 0, 0);
            }
        }

        #pragma unroll
        for (int mi = 0; mi < 2; mi++) {
            if (mi == 1 && !sact) continue;
            const bool diag = (mi == 0) ? (t == nt - 1) : (t == p);
            const int qrow = ((mi == 0) ? rowbase0 : rowbase1) + l16;
            #pragma unroll
            for (int nk = 0; nk < 4; nk++) {
                const int kc0 = j0 + nk * 16 + quad * 4;
                float pv[4];
                #pragma unroll
                for (int r = 0; r < 4; r++) {
                    float e = __expf(st[mi][nk][r]);
                    pv[r] = (diag && (kc0 + r > qrow)) ? 0.f : e;
                }
                uint2 w2 = make_uint2(pk_bf16(pv[0], pv[1]), pk_bf16(pv[2], pv[3]));
                *(uint2*)&Pl[wave][mi * 16 + l16][nk * 16 + quad * 4] = w2;
            }
        }

        #pragma unroll
        for (int ksp = 0; ksp < 2; ksp++) {
            bf16x8 bv[4];
            #pragma unroll
            for (int nd = 0; nd < 4; nd++) {
                const int d = nd * 16 + l16;
                bv[nd] = *(const bf16x8*)&Vt[cur][d][(ksp * 32 + quad * 8 + 8 * (d >> 3)) & 63];
            }
            #pragma unroll
            for (int mi = 0; mi < 2; mi++) {
                if (mi == 1 && !sact) continue;
                bf16x8 ap = *(const bf16x8*)&Pl[wave][mi * 16 + l16][ksp * 32 + quad * 8];
                acc_l[mi] = __builtin_amdgcn_mfma_f32_16x16x32_bf16(
                    ap, ones, acc_l[mi], 0, 0, 0);
                #pragma unroll
                for (int nd = 0; nd < 4; nd++)
                    acc_o[mi][nd] = __builtin_amdgcn_mfma_f32_16x16x32_bf16(
                        ap, bv[nd], acc_o[mi][nd], 0, 0, 0);
            }
        }

        if (hasNext) {
            *(uint4*)&Ks[nxt][sr][sc]     = ka;
            *(uint4*)&Ks[nxt][sr][sc + 8] = kb;
            ushort_t tmp[16];
            *(uint4*)&tmp[0] = va;
            *(uint4*)&tmp[8] = vb;
            #pragma unroll
            for (int e = 0; e < 16; e++) {
                int d = sc + e;
                Vt[nxt][d][(sr + 8 * (d >> 3)) & 63] = tmp[e];
            }
        }
        __syncthreads();
    }

    #pragma unroll
    for (int mi = 0; mi < 2; mi++) {
        const int rb = (mi == 0) ? rowbase0 : rowbase1;
        float inv[4];
        #pragma unroll
        for (int r = 0; r < 4; r++) inv[r] = 1.0f / acc_l[mi][r];
        #pragma unroll
        for (int nd = 0; nd < 4; nd++)
            #pragma unroll
            for (int r = 0; r < 4; r++) {
                int row = rb + quad * 4 + r;
                int col = h * HD + nd * 16 + l16;
                O[(size_t)row * (NQH * HD) + col] = f2bf(acc_o[mi][nd][r] * inv[r]);
            }
    }
}

// ---------------------------------------------------------------------------
// attn_v8: best-measured attn variant (44.0 us, round 2). 256-thread /
// 4-wave blocks owning 64 contiguous q-rows; grid = 32 heads x 32 strips =
// 1024 blocks; LDS 41 KB -> 3 blocks/CU resident. Every wave's diagonal
// tile is the LAST tile -> all 4 waves active on all nt = qi+1 iterations.
// Dispatch order: qi = bz<16 ? 31-bz : bz-16 (heaviest first). K from qkv,
// V^T from VtG, both DMA'd (global_load_lds w16) with the XOR source
// swizzle; double-buffered; one barrier per tile. [v9 (lane-local PV) and
// v10 (KV-split) both measured worse: 45.8 / 47.8 -> reverted.]
// ---------------------------------------------------------------------------
__global__ __launch_bounds__(256, 3) void attn_v8(
    const ushort_t* __restrict__ qkv, const ushort_t* __restrict__ VtG,
    ushort_t* __restrict__ O) {
    const int bx   = blockIdx.x;            // 1024 blocks
    const int h    = bx & 31;
    const int bz   = bx >> 5;               // 0..31
    const int qi   = (bz < 16) ? (31 - bz) : (bz - 16);
    const int kvh  = h >> 2;
    const int q0   = qi * 64;
    const int tid  = threadIdx.x;
    const int wave = tid >> 6;              // 0..3
    const int lane = tid & 63;
    const int quad = lane >> 4;
    const int l16  = lane & 15;

    __shared__ __align__(16) ushort_t Ks[2][64][64];   // 16 KB (DMA, swizzled)
    __shared__ __align__(16) ushort_t Vt[2][64][64];   // 16 KB (DMA, swizzled)
    __shared__ __align__(16) ushort_t Pl[4][16][72];   // 9 KB

    const int rb = q0 + wave * 16;          // this wave's 16 q-rows
    const int nt = qi + 1;                  // diag tile == last tile, all waves

    // Q B-frags (lane l16 = qrow), pre-scaled by (1/8)*log2(e) for exp2
    bf16x8 bq[2];
    #pragma unroll
    for (int ks = 0; ks < 2; ks++) {
        uint4 u = *(const uint4*)&qkv[(size_t)(rb + l16) * QKV_O
                                      + h * HD + ks * 32 + quad * 8];
        float f[8]; unpack8(f, u);
        const float QS = 0.18033688011112042f;   // 0.125 * log2(e)
        uint4 w = make_uint4(
            pk_bf16(f[0] * QS, f[1] * QS), pk_bf16(f[2] * QS, f[3] * QS),
            pk_bf16(f[4] * QS, f[5] * QS), pk_bf16(f[6] * QS, f[7] * QS));
        __builtin_memcpy(&bq[ks], &w, 16);
    }

    bf16x8 ones;
    #pragma unroll
    for (int e = 0; e < 8; e++) ones[e] = (__bf16)1.0f;

    f32x4 acc_o[4];
    f32x4 acc_l;
    {
        f32x4 z = {0.f, 0.f, 0.f, 0.f};
        acc_l = z;
        #pragma unroll
        for (int n = 0; n < 4; n++) acc_o[n] = z;
    }

    // DMA lane geometry (XOR swizzle on the source side); wave stages 16 rows
    // of K and 16 rows of V^T per tile (2 x 1KB DMA ops each).
    const int lr = lane >> 3;                 // row-in-group 0..7
    const int cg = ((lane & 7) ^ lr) << 3;    // swizzled global chunk (elems)
    const ushort_t* kbase = &qkv[(size_t)(wave * 16 + lr) * QKV_O + K_COL + kvh * HD + cg];
    const size_t    kr8   = (size_t)8 * QKV_O;
    const ushort_t* vbase = &VtG[(size_t)(kvh * HD + wave * 16 + lr) * S_LEN + cg];
    const size_t    vr8   = (size_t)8 * S_LEN;

    // ---- prologue: DMA tile 0 -> buffer 0 ----
    __builtin_amdgcn_global_load_lds(GLB(kbase),       LDSP(&Ks[0][wave * 16][0]),     16, 0, 0);
    __builtin_amdgcn_global_load_lds(GLB(kbase + kr8), LDSP(&Ks[0][wave * 16 + 8][0]), 16, 0, 0);
    __builtin_amdgcn_global_load_lds(GLB(vbase),       LDSP(&Vt[0][wave * 16][0]),     16, 0, 0);
    __builtin_amdgcn_global_load_lds(GLB(vbase + vr8), LDSP(&Vt[0][wave * 16 + 8][0]), 16, 0, 0);
    __syncthreads();

    for (int t = 0; t < nt; t++) {
        const int cur = t & 1, nxt = cur ^ 1;
        const int j0 = t * 64;

        // ---- DMA-prefetch tile t+1 -> alternate buffer (flies during compute)
        if (t + 1 < nt) {
            const size_t kj = (size_t)(j0 + 64) * QKV_O;
            __builtin_amdgcn_global_load_lds(GLB(kbase + kj),             LDSP(&Ks[nxt][wave * 16][0]),     16, 0, 0);
            __builtin_amdgcn_global_load_lds(GLB(kbase + kj + kr8),       LDSP(&Ks[nxt][wave * 16 + 8][0]), 16, 0, 0);
            __builtin_amdgcn_global_load_lds(GLB(vbase + (j0 + 64)),      LDSP(&Vt[nxt][wave * 16][0]),     16, 0, 0);
            __builtin_amdgcn_global_load_lds(GLB(vbase + (j0 + 64) + vr8),LDSP(&Vt[nxt][wave * 16 + 8][0]), 16, 0, 0);
        }

        // ---- S^T = K·Q^T ----
        f32x4 st[4];
        #pragma unroll
        for (int nk = 0; nk < 4; nk++) {
            f32x4 z = {0.f, 0.f, 0.f, 0.f};
            st[nk] = z;
        }
        #pragma unroll
        for (int ks = 0; ks < 2; ks++) {
            const int ca = (((ks << 2) + quad) ^ (l16 & 7)) << 3;
            bf16x8 ak[4];
            #pragma unroll
            for (int nk = 0; nk < 4; nk++)
                ak[nk] = *(const bf16x8*)&Ks[cur][nk * 16 + l16][ca];
            #pragma unroll
            for (int nk = 0; nk < 4; nk++)
                st[nk] = __builtin_amdgcn_mfma_f32_16x16x32_bf16(
                    ak[nk], bq[ks], st[nk], 0, 0, 0);
        }

        // ---- exp2 + causal mask (diag = last tile only), b64 P stores ----
        if (t == nt - 1) {
            const int qrow = rb + l16;
            #pragma unroll
            for (int nk = 0; nk < 4; nk++) {
                const int kc0 = j0 + nk * 16 + quad * 4;
                float pv[4];
                #pragma unroll
                for (int r = 0; r < 4; r++)
                    pv[r] = (kc0 + r > qrow) ? 0.f : exp2f(st[nk][r]);
                uint2 w2 = make_uint2(pk_bf16(pv[0], pv[1]), pk_bf16(pv[2], pv[3]));
                *(uint2*)&Pl[wave][l16][nk * 16 + quad * 4] = w2;
            }
        } else {
            #pragma unroll
            for (int nk = 0; nk < 4; nk++) {
                float pv[4];
                #pragma unroll
                for (int r = 0; r < 4; r++)
                    pv[r] = exp2f(st[nk][r]);
                uint2 w2 = make_uint2(pk_bf16(pv[0], pv[1]), pk_bf16(pv[2], pv[3]));
                *(uint2*)&Pl[wave][l16][nk * 16 + quad * 4] = w2;
            }
        }

        // ---- l += P·1 ; O += P·V ----
        #pragma unroll
        for (int ksp = 0; ksp < 2; ksp++) {
            const int ca = (((ksp << 2) + quad) ^ (l16 & 7)) << 3;
            bf16x8 bv[4];
            #pragma unroll
            for (int nd = 0; nd < 4; nd++)
                bv[nd] = *(const bf16x8*)&Vt[cur][nd * 16 + l16][ca];
            bf16x8 ap = *(const bf16x8*)&Pl[wave][l16][ksp * 32 + quad * 8];
            acc_l = __builtin_amdgcn_mfma_f32_16x16x32_bf16(
                ap, ones, acc_l, 0, 0, 0);
            #pragma unroll
            for (int nd = 0; nd < 4; nd++)
                acc_o[nd] = __builtin_amdgcn_mfma_f32_16x16x32_bf16(
                    ap, bv[nd], acc_o[nd], 0, 0, 0);
        }
        __syncthreads();   // one barrier/tile; compiler drains vmcnt here
    }

    // ---- epilogue: O / l ----
    float inv[4];
    #pragma unroll
    for (int r = 0; r < 4; r++) inv[r] = 1.0f / acc_l[r];
    #pragma unroll
    for (int nd = 0; nd < 4; nd++)
        #pragma unroll
        for (int r = 0; r < 4; r++) {
            int row = rb + quad * 4 + r;
            int col = h * HD + nd * 16 + l16;
            O[(size_t)row * (NQH * HD) + col] = f2bf(acc_o[nd][r] * inv[r]);
        }
}

// ---------------------------------------------------------------------------
extern "C" void kernel_launch(void* const* d_in, const int* in_sizes, int n_in,
                              void* d_out, int out_size, void* d_ws, size_t ws_size,
                              hipStream_t stream) {
    const float* x     = (const float*)d_in[0];  // [2048][2048] fp32
    const float* cosp  = (const float*)d_in[1];  // [2048][64]   fp32
    const float* sinp  = (const float*)d_in[2];  // [2048][64]   fp32
    const float* w_qkv = (const float*)d_in[3];  // [3072][2048] fp32
    const float* w_out = (const float*)d_in[4];  // [2048][2048] fp32
    float* out = (float*)d_out;                  // [2048][2048] fp32

    const size_t NQKV = (size_t)S_LEN * QKV_O;   // 6291456
    const size_t NH2  = (size_t)S_LEN * HID;     // 4194304
    const size_t NVT  = (size_t)(NKVH * HD) * S_LEN;  // 1048576
    const size_t need_old = 2 * (NQKV + NH2) * sizeof(ushort_t);        // 41.9 MB
    const size_t need_new = need_old + NVT * sizeof(ushort_t);          // 44.0 MB

    ushort_t* qkv = (ushort_t*)d_ws;             // bf16 [2048][3072]
    ushort_t* x_bf    = qkv + NQKV;
    ushort_t* attnO   = x_bf;                    // disjoint lifetimes
    ushort_t* wqkv_bf = x_bf + NH2;
    ushort_t* wout_bf = wqkv_bf + NQKV;
    ushort_t* VtG     = wout_bf + NH2;           // bf16 [512][2048]

    if (ws_size >= need_new) {
        convert3<<<XN8 / 256 + QN8 / 256 + ON8 / 256, 256, 0, stream>>>(
            x, w_qkv, w_out, x_bf, wqkv_bf, wout_bf);

        // 1) qkv(q,k w/ RoPE) + VtG(V^T) = x @ w_qkv^T  (64x128, dbuf)
        dim3 g1(QKV_O / 128, S_LEN / 64);
        gemm_bk64<false, true, true><<<g1, 256, 0, stream>>>(
            x_bf, wqkv_bf, qkv, S_LEN, QKV_O, HID, cosp, sinp, VtG);

        // 2) causal GQA attention (best-measured v8)
        attn_v8<<<32 * NQH, 256, 0, stream>>>(qkv, VtG, attnO);

        // 3) out = attnO @ w_out^T  (64x128, dbuf)
        dim3 g2(HID / 128, S_LEN / 64);
        gemm_bk64<true, false, false><<<g2, 256, 0, stream>>>(
            attnO, wout_bf, out, S_LEN, HID, HID, nullptr, nullptr, nullptr);
    } else if (ws_size >= need_old) {
        // round-13 path (no VtG room)
        convert3<<<XN8 / 256 + QN8 / 256 + ON8 / 256, 256, 0, stream>>>(
            x, w_qkv, w_out, x_bf, wqkv_bf, wout_bf);

        dim3 g1(QKV_O / 128, S_LEN / 64);
        gemm_bk64<false, true, false><<<g1, 256, 0, stream>>>(
            x_bf, wqkv_bf, qkv, S_LEN, QKV_O, HID, cosp, sinp, nullptr);

        attn_v5<<<16 * NQH, 256, 0, stream>>>(qkv, attnO);

        dim3 g2(HID / 128, S_LEN / 64);
        gemm_bk64<true, false, false><<<g2, 256, 0, stream>>>(
            attnO, wout_bf, out, S_LEN, HID, HID, nullptr, nullptr, nullptr);
    } else {
        ushort_t* attnO2 = qkv + NQKV;

        dim3 g1(QKV_O / 128, S_LEN / 128);
        gemm_bt<true, true, false><<<g1, 256, 0, stream>>>(x, w_qkv, qkv, S_LEN, QKV_O, HID);

        int rope_threads = S_LEN * (NQH + NKVH);
        rope_kernel<<<(rope_threads + 255) / 256, 256, 0, stream>>>(qkv, cosp, sinp);

        attn_v5<<<16 * NQH, 256, 0, stream>>>(qkv, attnO2);

        dim3 g2(HID / 128, S_LEN / 128);
        gemm_bt<false, true, true><<<g2, 256, 0, stream>>>(attnO2, w_out, out, S_LEN, HID, HID);
    }
}

// Round 11
// 199.929 us; speedup vs baseline: 1.0977x; 1.0074x over previous
//
#include <hip/hip_runtime.h>
#include <hip/hip_bf16.h>
#include <stdint.h>

// Problem constants (B=1). I/O dtype: fp32. Internals bf16 (MFMA path).
#define S_LEN 2048
#define HID   2048
#define NQH   32
#define NKVH  8
#define HD    64
#define QKV_O 3072      // (32 + 2*8) * 64
#define K_COL 2048      // col offset of K block in qkv row
#define V_COL 2560      // col offset of V block in qkv row

typedef unsigned short ushort_t;
typedef __bf16 bf16x8 __attribute__((ext_vector_type(8)));
typedef float  f32x4  __attribute__((ext_vector_type(4)));

#define GLB(p) ((const __attribute__((address_space(1))) void*)(p))
#define LDSP(p) ((__attribute__((address_space(3))) void*)(p))

__device__ __forceinline__ ushort_t f2bf(float f) {
    unsigned int x = __float_as_uint(f);
    unsigned int r = (x + 0x7fffu + ((x >> 16) & 1u)) >> 16;   // RNE
    return (ushort_t)r;
}
__device__ __forceinline__ unsigned int pk_bf16(float a, float b) {
    __hip_bfloat162 h = __float22bfloat162_rn(make_float2(a, b));
    unsigned int r;
    __builtin_memcpy(&r, &h, 4);
    return r;
}
__device__ __forceinline__ void unpack8(float* dst, uint4 u) {
    dst[0] = __uint_as_float(u.x << 16); dst[1] = __uint_as_float(u.x & 0xffff0000u);
    dst[2] = __uint_as_float(u.y << 16); dst[3] = __uint_as_float(u.y & 0xffff0000u);
    dst[4] = __uint_as_float(u.z << 16); dst[5] = __uint_as_float(u.z & 0xffff0000u);
    dst[6] = __uint_as_float(u.w << 16); dst[7] = __uint_as_float(u.w & 0xffff0000u);
}

// ---------------------------------------------------------------------------
// convert3: fp32 -> bf16 for x, w_qkv, w_out (unchanged)
// ---------------------------------------------------------------------------
#define XN8 (S_LEN * HID / 8)          // 524288
#define QN8 (QKV_O * HID / 8)          // 786432
#define ON8 (HID * HID / 8)            // 524288

__global__ __launch_bounds__(256) void convert3(
    const float* __restrict__ x, const float* __restrict__ wq,
    const float* __restrict__ wo, ushort_t* __restrict__ xb,
    ushort_t* __restrict__ wqb, ushort_t* __restrict__ wob) {
    int i = blockIdx.x * 256 + threadIdx.x;
    const float* s; ushort_t* d; int off;
    if (i < XN8)            { s = x;  d = xb;  off = i; }
    else if (i < XN8 + QN8) { s = wq; d = wqb; off = i - XN8; }
    else                    { s = wo; d = wob; off = i - XN8 - QN8; }
    const float4* sp = (const float4*)s + (size_t)off * 2;
    float4 a = sp[0], b = sp[1];
    *(uint4*)(d + (size_t)off * 8) = make_uint4(
        pk_bf16(a.x, a.y), pk_bf16(a.z, a.w),
        pk_bf16(b.x, b.y), pk_bf16(b.z, b.w));
}

// ---------------------------------------------------------------------------
// gemm_bk64: pure-bf16 GEMM, 64x128 tile, BK=64, XOR-swizzled LDS, dbuf,
// __syncthreads per k-step (ROUND-6 PROVEN FORM, 201.4 us total). The
// counted-vmcnt variant (rounds 7-9) is abandoned: it raced once (r7,
// absmax 0.089 nondeterministic) and the guide's regime-gate evidence
// (m228d/m230/m233) shows counted vmcnt is NULL at 2-phase structures like
// this one — tiny upside, real risk. Prologue stages k=0; each iteration
// issues the k+1 DMA into the alternate buffer BEFORE computing k, then one
// __syncthreads (vmcnt drain is structural but partially hidden by 3
// blocks/CU TLP).
// ROPE: fused in-lane RoPE epilogue for q/k tiles (bn < V_COL).
// VT:   V tiles (bn >= V_COL) stored transposed to VtG[vcol][seq].
// ---------------------------------------------------------------------------
template<bool CF32, bool ROPE, bool VT>
__global__ __launch_bounds__(256, 3) void gemm_bk64(
    const ushort_t* __restrict__ A, const ushort_t* __restrict__ Bt,
    void* __restrict__ Cp, int M, int N, int K,
    const float* __restrict__ cs, const float* __restrict__ sn,
    ushort_t* __restrict__ VtG) {
    __shared__ ushort_t As[2][64][64];     // 16 KB
    __shared__ ushort_t Bs[2][128][64];    // 32 KB

    const int t    = threadIdx.x;
    const int wave = t >> 6;
    const int lane = t & 63;
    const int quad = lane >> 4;
    const int l16  = lane & 15;
    const int wm   = (wave >> 1) << 5;
    const int wn   = (wave & 1)  << 6;
    const int bm   = blockIdx.y * 64;
    const int bn   = blockIdx.x * 128;
    const int lr   = lane >> 3;
    const int lc   = ((lane & 7) ^ lr) << 3;

    f32x4 acc[2][4];
    #pragma unroll
    for (int i = 0; i < 2; i++)
        #pragma unroll
        for (int j = 0; j < 4; j++) {
            f32x4 z = {0.f, 0.f, 0.f, 0.f};
            acc[i][j] = z;
        }

    const ushort_t* a0 = &A[(size_t)(bm + wave * 16 + lr) * K + lc];
    const ushort_t* b0 = &Bt[(size_t)(bn + wave * 32 + lr) * K + lc];
    const size_t r8 = (size_t)8 * K;

    // ---- prologue: stage k=0 into buffer 0 ----
    __builtin_amdgcn_global_load_lds(GLB(a0),          LDSP(&As[0][wave * 16][0]),      16, 0, 0);
    __builtin_amdgcn_global_load_lds(GLB(a0 + r8),     LDSP(&As[0][wave * 16 + 8][0]),  16, 0, 0);
    __builtin_amdgcn_global_load_lds(GLB(b0),          LDSP(&Bs[0][wave * 32][0]),      16, 0, 0);
    __builtin_amdgcn_global_load_lds(GLB(b0 + r8),     LDSP(&Bs[0][wave * 32 + 8][0]),  16, 0, 0);
    __builtin_amdgcn_global_load_lds(GLB(b0 + 2 * r8), LDSP(&Bs[0][wave * 32 + 16][0]), 16, 0, 0);
    __builtin_amdgcn_global_load_lds(GLB(b0 + 3 * r8), LDSP(&Bs[0][wave * 32 + 24][0]), 16, 0, 0);
    __syncthreads();

    const int nk = K >> 6;
    for (int kk = 0; kk < nk; kk++) {
        const int cur = kk & 1, nxt = cur ^ 1;

        // ---- issue DMA for k+1 into the alternate buffer (flies under MFMA)
        if (kk + 1 < nk) {
            const int k0 = (kk + 1) << 6;
            __builtin_amdgcn_global_load_lds(GLB(a0 + k0),          LDSP(&As[nxt][wave * 16][0]),      16, 0, 0);
            __builtin_amdgcn_global_load_lds(GLB(a0 + k0 + r8),     LDSP(&As[nxt][wave * 16 + 8][0]),  16, 0, 0);
            __builtin_amdgcn_global_load_lds(GLB(b0 + k0),          LDSP(&Bs[nxt][wave * 32][0]),      16, 0, 0);
            __builtin_amdgcn_global_load_lds(GLB(b0 + k0 + r8),     LDSP(&Bs[nxt][wave * 32 + 8][0]),  16, 0, 0);
            __builtin_amdgcn_global_load_lds(GLB(b0 + k0 + 2 * r8), LDSP(&Bs[nxt][wave * 32 + 16][0]), 16, 0, 0);
            __builtin_amdgcn_global_load_lds(GLB(b0 + k0 + 3 * r8), LDSP(&Bs[nxt][wave * 32 + 24][0]), 16, 0, 0);
        }

        // ---- compute current buffer ----
        #pragma unroll
        for (int ks = 0; ks < 2; ks++) {
            const int ca = (((ks << 2) + quad) ^ (l16 & 7)) << 3;
            bf16x8 af[2], bfr[4];
            #pragma unroll
            for (int i = 0; i < 2; i++)
                af[i] = *(const bf16x8*)&As[cur][wm + i * 16 + l16][ca];
            #pragma unroll
            for (int j = 0; j < 4; j++)
                bfr[j] = *(const bf16x8*)&Bs[cur][wn + j * 16 + l16][ca];

            #pragma unroll
            for (int i = 0; i < 2; i++)
                #pragma unroll
                for (int j = 0; j < 4; j++)
                    acc[i][j] = __builtin_amdgcn_mfma_f32_16x16x32_bf16(
                        af[i], bfr[j], acc[i][j], 0, 0, 0);
        }
        __syncthreads();   // one barrier/k-step; drains vmcnt -> buf[nxt] ready
    }

    // Epilogue: C/D layout col=lane&15 (+nd*16), row=quad*4+reg
    if (ROPE && bn < V_COL) {
        #pragma unroll
        for (int i = 0; i < 2; i++)
            #pragma unroll
            for (int r = 0; r < 4; r++) {
                const int srow = bm + wm + i * 16 + quad * 4 + r;
                float cv[4], sv[4], o[4];
                #pragma unroll
                for (int nd = 0; nd < 4; nd++) {
                    const int d = nd * 16 + l16;
                    cv[nd] = cs[srow * HD + d];
                    sv[nd] = sn[srow * HD + d];
                }
                o[0] = acc[i][0][r] * cv[0] - acc[i][2][r] * sv[0];
                o[1] = acc[i][1][r] * cv[1] - acc[i][3][r] * sv[1];
                o[2] = acc[i][2][r] * cv[2] + acc[i][0][r] * sv[2];
                o[3] = acc[i][3][r] * cv[3] + acc[i][1][r] * sv[3];
                #pragma unroll
                for (int nd = 0; nd < 4; nd++) {
                    const int col = bn + wn + nd * 16 + l16;
                    ((ushort_t*)Cp)[(size_t)srow * N + col] = f2bf(o[nd]);
                }
            }
    } else if (VT && bn >= V_COL) {
        #pragma unroll
        for (int i = 0; i < 2; i++) {
            const int srow0 = bm + wm + i * 16 + quad * 4;
            #pragma unroll
            for (int nd = 0; nd < 4; nd++) {
                const int vcol = bn + wn + nd * 16 + l16 - V_COL;
                uint2 w2 = make_uint2(
                    pk_bf16(acc[i][nd][0], acc[i][nd][1]),
                    pk_bf16(acc[i][nd][2], acc[i][nd][3]));
                *(uint2*)&VtG[(size_t)vcol * S_LEN + srow0] = w2;
            }
        }
    } else {
        #pragma unroll
        for (int i = 0; i < 2; i++)
            #pragma unroll
            for (int j = 0; j < 4; j++)
                #pragma unroll
                for (int r = 0; r < 4; r++) {
                    int row = bm + wm + i * 16 + quad * 4 + r;
                    int col = bn + wn + j * 16 + l16;
                    if (CF32)
                        ((float*)Cp)[(size_t)row * N + col] = acc[i][j][r];
                    else
                        ((ushort_t*)Cp)[(size_t)row * N + col] = f2bf(acc[i][j][r]);
                }
    }
}

// ---------------------------------------------------------------------------
// Fallback GEMM with fused fp32->bf16 staging (small-ws path; unchanged)
// ---------------------------------------------------------------------------
template<bool AF32, bool BF32, bool CF32>
__global__ __launch_bounds__(256) void gemm_bt(
    const void* __restrict__ Ap, const void* __restrict__ Bp,
    void* __restrict__ Cp, int M, int N, int K) {
    __shared__ ushort_t As[128][40];
    __shared__ ushort_t Bs[128][40];

    const int t    = threadIdx.x;
    const int wave = t >> 6;
    const int lane = t & 63;
    const int quad = lane >> 4;
    const int l16  = lane & 15;
    const int wm   = (wave >> 1) << 6;
    const int wn   = (wave & 1)  << 6;
    const int bm   = blockIdx.y * 128;
    const int bn   = blockIdx.x * 128;
    const int sr   = t >> 2;
    const int sc   = (t & 3) << 3;

    f32x4 acc[4][4];
    #pragma unroll
    for (int i = 0; i < 4; i++)
        #pragma unroll
        for (int j = 0; j < 4; j++) {
            f32x4 z = {0.f, 0.f, 0.f, 0.f};
            acc[i][j] = z;
        }

    for (int k0 = 0; k0 < K; k0 += 32) {
        __syncthreads();
        if (AF32) {
            const float* A = (const float*)Ap;
            const float* p0 = &A[(size_t)(bm + sr) * K + k0 + sc];
            const float* p1 = &A[(size_t)(bm + sr + 64) * K + k0 + sc];
            float4 a0 = *(const float4*)p0, a1 = *(const float4*)(p0 + 4);
            float4 b0 = *(const float4*)p1, b1 = *(const float4*)(p1 + 4);
            *(uint4*)&As[sr][sc] = make_uint4(
                pk_bf16(a0.x, a0.y), pk_bf16(a0.z, a0.w),
                pk_bf16(a1.x, a1.y), pk_bf16(a1.z, a1.w));
            *(uint4*)&As[sr + 64][sc] = make_uint4(
                pk_bf16(b0.x, b0.y), pk_bf16(b0.z, b0.w),
                pk_bf16(b1.x, b1.y), pk_bf16(b1.z, b1.w));
        } else {
            const ushort_t* A = (const ushort_t*)Ap;
            *(uint4*)&As[sr][sc]      = *(const uint4*)&A[(size_t)(bm + sr) * K + k0 + sc];
            *(uint4*)&As[sr + 64][sc] = *(const uint4*)&A[(size_t)(bm + sr + 64) * K + k0 + sc];
        }
        if (BF32) {
            const float* B = (const float*)Bp;
            const float* p0 = &B[(size_t)(bn + sr) * K + k0 + sc];
            const float* p1 = &B[(size_t)(bn + sr + 64) * K + k0 + sc];
            float4 a0 = *(const float4*)p0, a1 = *(const float4*)(p0 + 4);
            float4 b0 = *(const float4*)p1, b1 = *(const float4*)(p1 + 4);
            *(uint4*)&Bs[sr][sc] = make_uint4(
                pk_bf16(a0.x, a0.y), pk_bf16(a0.z, a0.w),
                pk_bf16(a1.x, a1.y), pk_bf16(a1.z, a1.w));
            *(uint4*)&Bs[sr + 64][sc] = make_uint4(
                pk_bf16(b0.x, b0.y), pk_bf16(b0.z, b0.w),
                pk_bf16(b1.x, b1.y), pk_bf16(b1.z, b1.w));
        } else {
            const ushort_t* B = (const ushort_t*)Bp;
            *(uint4*)&Bs[sr][sc]      = *(const uint4*)&B[(size_t)(bn + sr) * K + k0 + sc];
            *(uint4*)&Bs[sr + 64][sc] = *(const uint4*)&B[(size_t)(bn + sr + 64) * K + k0 + sc];
        }
        __syncthreads();

        bf16x8 af[4], bfr[4];
        #pragma unroll
        for (int i = 0; i < 4; i++)
            af[i] = *(const bf16x8*)&As[wm + i * 16 + l16][quad * 8];
        #pragma unroll
        for (int j = 0; j < 4; j++)
            bfr[j] = *(const bf16x8*)&Bs[wn + j * 16 + l16][quad * 8];

        #pragma unroll
        for (int i = 0; i < 4; i++)
            #pragma unroll
            for (int j = 0; j < 4; j++)
                acc[i][j] = __builtin_amdgcn_mfma_f32_16x16x32_bf16(
                    af[i], bfr[j], acc[i][j], 0, 0, 0);
    }

    #pragma unroll
    for (int i = 0; i < 4; i++)
        #pragma unroll
        for (int j = 0; j < 4; j++)
            #pragma unroll
            for (int r = 0; r < 4; r++) {
                int row = bm + wm + i * 16 + quad * 4 + r;
                int col = bn + wn + j * 16 + l16;
                if (CF32)
                    ((float*)Cp)[(size_t)row * N + col] = acc[i][j][r];
                else
                    ((ushort_t*)Cp)[(size_t)row * N + col] = f2bf(acc[i][j][r]);
            }
}

// ---------------------------------------------------------------------------
// RoPE standalone (fallback path only)
// ---------------------------------------------------------------------------
__global__ __launch_bounds__(256) void rope_kernel(
    ushort_t* __restrict__ qkv, const float* __restrict__ cs,
    const float* __restrict__ sn) {
    int idx = blockIdx.x * 256 + threadIdx.x;
    if (idx >= S_LEN * (NQH + NKVH)) return;
    int s  = idx / (NQH + NKVH);
    int hh = idx - s * (NQH + NKVH);

    ushort_t* p = &qkv[(size_t)s * QKV_O + hh * HD];
    const uint4* p4 = (const uint4*)p;
    float v[HD], c[HD], sv[HD];
    #pragma unroll
    for (int b = 0; b < 8; b++) unpack8(&v[b * 8], p4[b]);
    const float4* c4 = (const float4*)&cs[s * HD];
    const float4* s4 = (const float4*)&sn[s * HD];
    #pragma unroll
    for (int b = 0; b < 16; b++) {
        ((float4*)c)[b]  = c4[b];
        ((float4*)sv)[b] = s4[b];
    }
    float o[HD];
    #pragma unroll
    for (int d = 0; d < 32; d++) {
        o[d]      = v[d] * c[d]           - v[d + 32] * sv[d];
        o[d + 32] = v[d + 32] * c[d + 32] + v[d]      * sv[d + 32];
    }
    unsigned int* pw = (unsigned int*)p;
    #pragma unroll
    for (int d = 0; d < HD; d += 2)
        pw[d >> 1] = pk_bf16(o[d], o[d + 1]);
}

// ---------------------------------------------------------------------------
// attn_v5: round-12/13 kernel (fallback paths; reads V from qkv)
// ---------------------------------------------------------------------------
__global__ __launch_bounds__(256) void attn_v5(
    const ushort_t* __restrict__ qkv, ushort_t* __restrict__ O) {
    const int bx   = blockIdx.x;
    const int h    = bx & 31;
    const int p    = bx >> 5;
    const int kvh  = h >> 2;
    const int q0d  = (31 - p) * 64;
    const int q0s  = p * 64;
    const int tid  = threadIdx.x;
    const int wave = tid >> 6;
    const int lane = tid & 63;
    const int quad = lane >> 4;
    const int l16  = lane & 15;

    __shared__ __align__(16) ushort_t Ks[2][64][72];
    __shared__ __align__(16) ushort_t Vt[2][64][72];
    __shared__ __align__(16) ushort_t Pl[4][32][72];

    const int rowbase0 = q0d + wave * 16;
    const int rowbase1 = q0s + wave * 16;

    bf16x8 bq[2][2];
    #pragma unroll
    for (int mi = 0; mi < 2; mi++) {
        const int rb = (mi == 0) ? rowbase0 : rowbase1;
        #pragma unroll
        for (int ks = 0; ks < 2; ks++) {
            uint4 u = *(const uint4*)&qkv[(size_t)(rb + l16) * QKV_O
                                          + h * HD + ks * 32 + quad * 8];
            float f[8]; unpack8(f, u);
            uint4 w = make_uint4(
                pk_bf16(f[0] * 0.125f, f[1] * 0.125f),
                pk_bf16(f[2] * 0.125f, f[3] * 0.125f),
                pk_bf16(f[4] * 0.125f, f[5] * 0.125f),
                pk_bf16(f[6] * 0.125f, f[7] * 0.125f));
            __builtin_memcpy(&bq[mi][ks], &w, 16);
        }
    }

    bf16x8 ones;
    #pragma unroll
    for (int e = 0; e < 8; e++) ones[e] = (__bf16)1.0f;

    f32x4 acc_o[2][4];
    f32x4 acc_l[2];
    #pragma unroll
    for (int mi = 0; mi < 2; mi++) {
        f32x4 z = {0.f, 0.f, 0.f, 0.f};
        acc_l[mi] = z;
        #pragma unroll
        for (int n = 0; n < 4; n++) acc_o[mi][n] = z;
    }

    const int nt = 32 - p;
    const int sr = tid >> 2;
    const int sc = (tid & 3) << 4;

    {
        const ushort_t* kp = &qkv[(size_t)sr * QKV_O + K_COL + kvh * HD + sc];
        *(uint4*)&Ks[0][sr][sc]     = *(const uint4*)kp;
        *(uint4*)&Ks[0][sr][sc + 8] = *(const uint4*)(kp + 8);
        const ushort_t* vp = &qkv[(size_t)sr * QKV_O + V_COL + kvh * HD + sc];
        ushort_t tmp[16];
        *(uint4*)&tmp[0] = *(const uint4*)vp;
        *(uint4*)&tmp[8] = *(const uint4*)(vp + 8);
        #pragma unroll
        for (int e = 0; e < 16; e++) {
            int d = sc + e;
            Vt[0][d][(sr + 8 * (d >> 3)) & 63] = tmp[e];
        }
    }
    __syncthreads();

    for (int t = 0; t < nt; t++) {
        const int cur = t & 1, nxt = cur ^ 1;
        const int j0 = t * 64;
        const bool hasNext = (t + 1 < nt);

        uint4 ka, kb, va, vb;
        if (hasNext) {
            const size_t rbase = (size_t)(j0 + 64 + sr) * QKV_O;
            const ushort_t* kp = &qkv[rbase + K_COL + kvh * HD + sc];
            ka = *(const uint4*)kp; kb = *(const uint4*)(kp + 8);
            const ushort_t* vp = &qkv[rbase + V_COL + kvh * HD + sc];
            va = *(const uint4*)vp; vb = *(const uint4*)(vp + 8);
        }

        const bool sact = (t <= p);

        f32x4 st[2][4];
        #pragma unroll
        for (int mi = 0; mi < 2; mi++)
            #pragma unroll
            for (int nk = 0; nk < 4; nk++) {
                f32x4 z = {0.f, 0.f, 0.f, 0.f};
                st[mi][nk] = z;
            }
        #pragma unroll
        for (int ks = 0; ks < 2; ks++) {
            bf16x8 ak[4];
            #pragma unroll
            for (int nk = 0; nk < 4; nk++)
                ak[nk] = *(const bf16x8*)&Ks[cur][nk * 16 + l16][ks * 32 + quad * 8];
            #pragma unroll
            for (int mi = 0; mi < 2; mi++) {
                if (mi == 1 && !sact) continue;
                #pragma unroll
                for (int nk = 0; nk < 4; nk++)
                    st[mi][nk] = __builtin_amdgcn_mfma_f32_16x16x32_bf16(
                        ak[nk], bq[mi][ks], st[mi][nk], 0, 0, 0);
            }
        }

        #pragma unroll
        for (int mi = 0; mi < 2; mi++) {
            if (mi == 1 && !sact) continue;
            const bool diag = (mi == 0) ? (t == nt - 1) : (t == p);
            const int qrow = ((mi == 0) ? rowbase0 : rowbase1) + l16;
            #pragma unroll
            for (int nk = 0; nk < 4; nk++) {
                const int kc0 = j0 + nk * 16 + quad * 4;
                float pv[4];
                #pragma unroll
                for (int r = 0; r < 4; r++) {
                    float e = __expf(st[mi][nk][r]);
                    pv[r] = (diag && (kc0 + r > qrow)) ? 0.f : e;
                }
                uint2 w2 = make_uint2(pk_bf16(pv[0], pv[1]), pk_bf16(pv[2], pv[3]));
                *(uint2*)&Pl[wave][mi * 16 + l16][nk * 16 + quad * 4] = w2;
            }
        }

        #pragma unroll
        for (int ksp = 0; ksp < 2; ksp++) {
            bf16x8 bv[4];
            #pragma unroll
            for (int nd = 0; nd < 4; nd++) {
                const int d = nd * 16 + l16;
                bv[nd] = *(const bf16x8*)&Vt[cur][d][(ksp * 32 + quad * 8 + 8 * (d >> 3)) & 63];
            }
            #pragma unroll
            for (int mi = 0; mi < 2; mi++) {
                if (mi == 1 && !sact) continue;
                bf16x8 ap = *(const bf16x8*)&Pl[wave][mi * 16 + l16][ksp * 32 + quad * 8];
                acc_l[mi] = __builtin_amdgcn_mfma_f32_16x16x32_bf16(
                    ap, ones, acc_l[mi], 0, 0, 0);
                #pragma unroll
                for (int nd = 0; nd < 4; nd++)
                    acc_o[mi][nd] = __builtin_amdgcn_mfma_f32_16x16x32_bf16(
                        ap, bv[nd], acc_o[mi][nd], 0, 0, 0);
            }
        }

        if (hasNext) {
            *(uint4*)&Ks[nxt][sr][sc]     = ka;
            *(uint4*)&Ks[nxt][sr][sc + 8] = kb;
            ushort_t tmp[16];
            *(uint4*)&tmp[0] = va;
            *(uint4*)&tmp[8] = vb;
            #pragma unroll
            for (int e = 0; e < 16; e++) {
                int d = sc + e;
                Vt[nxt][d][(sr + 8 * (d >> 3)) & 63] = tmp[e];
            }
        }
        __syncthreads();
    }

    #pragma unroll
    for (int mi = 0; mi < 2; mi++) {
        const int rb = (mi == 0) ? rowbase0 : rowbase1;
        float inv[4];
        #pragma unroll
        for (int r = 0; r < 4; r++) inv[r] = 1.0f / acc_l[mi][r];
        #pragma unroll
        for (int nd = 0; nd < 4; nd++)
            #pragma unroll
            for (int r = 0; r < 4; r++) {
                int row = rb + quad * 4 + r;
                int col = h * HD + nd * 16 + l16;
                O[(size_t)row * (NQH * HD) + col] = f2bf(acc_o[mi][nd][r] * inv[r]);
            }
    }
}

// ---------------------------------------------------------------------------
// attn_v8: round-6 proven form (__syncthreads per tile, 45.3 us) + T5
// s_setprio(1) around the MFMA clusters. Mechanism gate checked: T5 needs
// wave role-diversity; here 3 independent blocks/CU sit at DIFFERENT tile
// indices (different qi -> staggered phases), matching m191's attn context
// (+4-7%), unlike m190's lockstep GEMM null. setprio is a pure scheduler
// hint -- zero correctness risk. GEMMs get no setprio (m190: hurts).
// ---------------------------------------------------------------------------
__global__ __launch_bounds__(256, 3) void attn_v8(
    const ushort_t* __restrict__ qkv, const ushort_t* __restrict__ VtG,
    ushort_t* __restrict__ O) {
    const int bx   = blockIdx.x;            // 1024 blocks
    const int h    = bx & 31;
    const int bz   = bx >> 5;               // 0..31
    const int qi   = (bz < 16) ? (31 - bz) : (bz - 16);
    const int kvh  = h >> 2;
    const int q0   = qi * 64;
    const int tid  = threadIdx.x;
    const int wave = tid >> 6;              // 0..3
    const int lane = tid & 63;
    const int quad = lane >> 4;
    const int l16  = lane & 15;

    __shared__ __align__(16) ushort_t Ks[2][64][64];   // 16 KB (DMA, swizzled)
    __shared__ __align__(16) ushort_t Vt[2][64][64];   // 16 KB (DMA, swizzled)
    __shared__ __align__(16) ushort_t Pl[4][16][72];   // 9 KB

    const int rb = q0 + wave * 16;          // this wave's 16 q-rows
    const int nt = qi + 1;                  // diag tile == last tile, all waves

    // Q B-frags (lane l16 = qrow), pre-scaled by (1/8)*log2(e) for exp2
    bf16x8 bq[2];
    #pragma unroll
    for (int ks = 0; ks < 2; ks++) {
        uint4 u = *(const uint4*)&qkv[(size_t)(rb + l16) * QKV_O
                                      + h * HD + ks * 32 + quad * 8];
        float f[8]; unpack8(f, u);
        const float QS = 0.18033688011112042f;   // 0.125 * log2(e)
        uint4 w = make_uint4(
            pk_bf16(f[0] * QS, f[1] * QS), pk_bf16(f[2] * QS, f[3] * QS),
            pk_bf16(f[4] * QS, f[5] * QS), pk_bf16(f[6] * QS, f[7] * QS));
        __builtin_memcpy(&bq[ks], &w, 16);
    }

    bf16x8 ones;
    #pragma unroll
    for (int e = 0; e < 8; e++) ones[e] = (__bf16)1.0f;

    f32x4 acc_o[4];
    f32x4 acc_l;
    {
        f32x4 z = {0.f, 0.f, 0.f, 0.f};
        acc_l = z;
        #pragma unroll
        for (int n = 0; n < 4; n++) acc_o[n] = z;
    }

    // DMA lane geometry (XOR swizzle on the source side); wave stages 16 rows
    // of K and 16 rows of V^T per tile (2 x 1KB DMA ops each).
    const int lr = lane >> 3;                 // row-in-group 0..7
    const int cg = ((lane & 7) ^ lr) << 3;    // swizzled global chunk (elems)
    const ushort_t* kbase = &qkv[(size_t)(wave * 16 + lr) * QKV_O + K_COL + kvh * HD + cg];
    const size_t    kr8   = (size_t)8 * QKV_O;
    const ushort_t* vbase = &VtG[(size_t)(kvh * HD + wave * 16 + lr) * S_LEN + cg];
    const size_t    vr8   = (size_t)8 * S_LEN;

    // ---- prologue: DMA tile 0 -> buffer 0 ----
    __builtin_amdgcn_global_load_lds(GLB(kbase),       LDSP(&Ks[0][wave * 16][0]),     16, 0, 0);
    __builtin_amdgcn_global_load_lds(GLB(kbase + kr8), LDSP(&Ks[0][wave * 16 + 8][0]), 16, 0, 0);
    __builtin_amdgcn_global_load_lds(GLB(vbase),       LDSP(&Vt[0][wave * 16][0]),     16, 0, 0);
    __builtin_amdgcn_global_load_lds(GLB(vbase + vr8), LDSP(&Vt[0][wave * 16 + 8][0]), 16, 0, 0);
    __syncthreads();

    for (int t = 0; t < nt; t++) {
        const int cur = t & 1, nxt = cur ^ 1;
        const int j0 = t * 64;

        // ---- DMA-prefetch tile t+1 -> alternate buffer (flies during compute)
        if (t + 1 < nt) {
            const size_t kj = (size_t)(j0 + 64) * QKV_O;
            __builtin_amdgcn_global_load_lds(GLB(kbase + kj),             LDSP(&Ks[nxt][wave * 16][0]),     16, 0, 0);
            __builtin_amdgcn_global_load_lds(GLB(kbase + kj + kr8),       LDSP(&Ks[nxt][wave * 16 + 8][0]), 16, 0, 0);
            __builtin_amdgcn_global_load_lds(GLB(vbase + (j0 + 64)),      LDSP(&Vt[nxt][wave * 16][0]),     16, 0, 0);
            __builtin_amdgcn_global_load_lds(GLB(vbase + (j0 + 64) + vr8),LDSP(&Vt[nxt][wave * 16 + 8][0]), 16, 0, 0);
        }

        // ---- S^T = K·Q^T (setprio: favor MFMA-entering waves) ----
        f32x4 st[4];
        #pragma unroll
        for (int nk = 0; nk < 4; nk++) {
            f32x4 z = {0.f, 0.f, 0.f, 0.f};
            st[nk] = z;
        }
        __builtin_amdgcn_s_setprio(1);
        #pragma unroll
        for (int ks = 0; ks < 2; ks++) {
            const int ca = (((ks << 2) + quad) ^ (l16 & 7)) << 3;
            bf16x8 ak[4];
            #pragma unroll
            for (int nk = 0; nk < 4; nk++)
                ak[nk] = *(const bf16x8*)&Ks[cur][nk * 16 + l16][ca];
            #pragma unroll
            for (int nk = 0; nk < 4; nk++)
                st[nk] = __builtin_amdgcn_mfma_f32_16x16x32_bf16(
                    ak[nk], bq[ks], st[nk], 0, 0, 0);
        }
        __builtin_amdgcn_s_setprio(0);

        // ---- exp2 + causal mask (diag = last tile only), b64 P stores ----
        if (t == nt - 1) {
            const int qrow = rb + l16;
            #pragma unroll
            for (int nk = 0; nk < 4; nk++) {
                const int kc0 = j0 + nk * 16 + quad * 4;
                float pv[4];
                #pragma unroll
                for (int r = 0; r < 4; r++)
                    pv[r] = (kc0 + r > qrow) ? 0.f : exp2f(st[nk][r]);
                uint2 w2 = make_uint2(pk_bf16(pv[0], pv[1]), pk_bf16(pv[2], pv[3]));
                *(uint2*)&Pl[wave][l16][nk * 16 + quad * 4] = w2;
            }
        } else {
            #pragma unroll
            for (int nk = 0; nk < 4; nk++) {
                float pv[4];
                #pragma unroll
                for (int r = 0; r < 4; r++)
                    pv[r] = exp2f(st[nk][r]);
                uint2 w2 = make_uint2(pk_bf16(pv[0], pv[1]), pk_bf16(pv[2], pv[3]));
                *(uint2*)&Pl[wave][l16][nk * 16 + quad * 4] = w2;
            }
        }

        // ---- l += P·1 ; O += P·V (setprio around the MFMA cluster) ----
        __builtin_amdgcn_s_setprio(1);
        #pragma unroll
        for (int ksp = 0; ksp < 2; ksp++) {
            const int ca = (((ksp << 2) + quad) ^ (l16 & 7)) << 3;
            bf16x8 bv[4];
            #pragma unroll
            for (int nd = 0; nd < 4; nd++)
                bv[nd] = *(const bf16x8*)&Vt[cur][nd * 16 + l16][ca];
            bf16x8 ap = *(const bf16x8*)&Pl[wave][l16][ksp * 32 + quad * 8];
            acc_l = __builtin_amdgcn_mfma_f32_16x16x32_bf16(
                ap, ones, acc_l, 0, 0, 0);
            #pragma unroll
            for (int nd = 0; nd < 4; nd++)
                acc_o[nd] = __builtin_amdgcn_mfma_f32_16x16x32_bf16(
                    ap, bv[nd], acc_o[nd], 0, 0, 0);
        }
        __builtin_amdgcn_s_setprio(0);
        __syncthreads();   // one barrier/tile; compiler drains vmcnt here
    }

    // ---- epilogue: O / l ----
    float inv[4];
    #pragma unroll
    for (int r = 0; r < 4; r++) inv[r] = 1.0f / acc_l[r];
    #pragma unroll
    for (int nd = 0; nd < 4; nd++)
        #pragma unroll
        for (int r = 0; r < 4; r++) {
            int row = rb + quad * 4 + r;
            int col = h * HD + nd * 16 + l16;
            O[(size_t)row * (NQH * HD) + col] = f2bf(acc_o[nd][r] * inv[r]);
        }
}

// ---------------------------------------------------------------------------
extern "C" void kernel_launch(void* const* d_in, const int* in_sizes, int n_in,
                              void* d_out, int out_size, void* d_ws, size_t ws_size,
                              hipStream_t stream) {
    const float* x     = (const float*)d_in[0];  // [2048][2048] fp32
    const float* cosp  = (const float*)d_in[1];  // [2048][64]   fp32
    const float* sinp  = (const float*)d_in[2];  // [2048][64]   fp32
    const float* w_qkv = (const float*)d_in[3];  // [3072][2048] fp32
    const float* w_out = (const float*)d_in[4];  // [2048][2048] fp32
    float* out = (float*)d_out;                  // [2048][2048] fp32

    const size_t NQKV = (size_t)S_LEN * QKV_O;   // 6291456
    const size_t NH2  = (size_t)S_LEN * HID;     // 4194304
    const size_t NVT  = (size_t)(NKVH * HD) * S_LEN;  // 1048576
    const size_t need_old = 2 * (NQKV + NH2) * sizeof(ushort_t);        // 41.9 MB
    const size_t need_new = need_old + NVT * sizeof(ushort_t);          // 44.0 MB

    ushort_t* qkv = (ushort_t*)d_ws;             // bf16 [2048][3072]
    ushort_t* x_bf    = qkv + NQKV;
    ushort_t* attnO   = x_bf;                    // disjoint lifetimes
    ushort_t* wqkv_bf = x_bf + NH2;
    ushort_t* wout_bf = wqkv_bf + NQKV;
    ushort_t* VtG     = wout_bf + NH2;           // bf16 [512][2048]

    if (ws_size >= need_new) {
        convert3<<<XN8 / 256 + QN8 / 256 + ON8 / 256, 256, 0, stream>>>(
            x, w_qkv, w_out, x_bf, wqkv_bf, wout_bf);

        // 1) qkv(q,k w/ RoPE) + VtG(V^T) = x @ w_qkv^T  (64x128, dbuf)
        dim3 g1(QKV_O / 128, S_LEN / 64);
        gemm_bk64<false, true, true><<<g1, 256, 0, stream>>>(
            x_bf, wqkv_bf, qkv, S_LEN, QKV_O, HID, cosp, sinp, VtG);

        // 2) causal GQA attention (v8 + setprio)
        attn_v8<<<32 * NQH, 256, 0, stream>>>(qkv, VtG, attnO);

        // 3) out = attnO @ w_out^T  (64x128, dbuf)
        dim3 g2(HID / 128, S_LEN / 64);
        gemm_bk64<true, false, false><<<g2, 256, 0, stream>>>(
            attnO, wout_bf, out, S_LEN, HID, HID, nullptr, nullptr, nullptr);
    } else if (ws_size >= need_old) {
        // round-13 path (no VtG room)
        convert3<<<XN8 / 256 + QN8 / 256 + ON8 / 256, 256, 0, stream>>>(
            x, w_qkv, w_out, x_bf, wqkv_bf, wout_bf);

        dim3 g1(QKV_O / 128, S_LEN / 64);
        gemm_bk64<false, true, false><<<g1, 256, 0, stream>>>(
            x_bf, wqkv_bf, qkv, S_LEN, QKV_O, HID, cosp, sinp, nullptr);

        attn_v5<<<16 * NQH, 256, 0, stream>>>(qkv, attnO);

        dim3 g2(HID / 128, S_LEN / 64);
        gemm_bk64<true, false, false><<<g2, 256, 0, stream>>>(
            attnO, wout_bf, out, S_LEN, HID, HID, nullptr, nullptr, nullptr);
    } else {
        ushort_t* attnO2 = qkv + NQKV;

        dim3 g1(QKV_O / 128, S_LEN / 128);
        gemm_bt<true, true, false><<<g1, 256, 0, stream>>>(x, w_qkv, qkv, S_LEN, QKV_O, HID);

        int rope_threads = S_LEN * (NQH + NKVH);
        rope_kernel<<<(rope_threads + 255) / 256, 256, 0, stream>>>(qkv, cosp, sinp);

        attn_v5<<<16 * NQH, 256, 0, stream>>>(qkv, attnO2);

        dim3 g2(HID / 128, S_LEN / 128);
        gemm_bt<false, true, true><<<g2, 256, 0, stream>>>(attnO2, w_out, out, S_LEN, HID, HID);
    }
}

// Round 13
// 197.338 us; speedup vs baseline: 1.1121x; 1.0131x over previous
//
#include <hip/hip_runtime.h>
#include <hip/hip_bf16.h>
#include <stdint.h>

// Problem constants (B=1). I/O dtype: fp32. Internals bf16 (MFMA path).
#define S_LEN 2048
#define HID   2048
#define NQH   32
#define NKVH  8
#define HD    64
#define QKV_O 3072      // (32 + 2*8) * 64
#define K_COL 2048      // col offset of K block in qkv row
#define V_COL 2560      // col offset of V block in qkv row

typedef unsigned short ushort_t;
typedef __bf16 bf16x8 __attribute__((ext_vector_type(8)));
typedef float  f32x4  __attribute__((ext_vector_type(4)));

#define GLB(p) ((const __attribute__((address_space(1))) void*)(p))
#define LDSP(p) ((__attribute__((address_space(3))) void*)(p))

__device__ __forceinline__ ushort_t f2bf(float f) {
    unsigned int x = __float_as_uint(f);
    unsigned int r = (x + 0x7fffu + ((x >> 16) & 1u)) >> 16;   // RNE
    return (ushort_t)r;
}
__device__ __forceinline__ unsigned int pk_bf16(float a, float b) {
    __hip_bfloat162 h = __float22bfloat162_rn(make_float2(a, b));
    unsigned int r;
    __builtin_memcpy(&r, &h, 4);
    return r;
}
__device__ __forceinline__ void unpack8(float* dst, uint4 u) {
    dst[0] = __uint_as_float(u.x << 16); dst[1] = __uint_as_float(u.x & 0xffff0000u);
    dst[2] = __uint_as_float(u.y << 16); dst[3] = __uint_as_float(u.y & 0xffff0000u);
    dst[4] = __uint_as_float(u.z << 16); dst[5] = __uint_as_float(u.z & 0xffff0000u);
    dst[6] = __uint_as_float(u.w << 16); dst[7] = __uint_as_float(u.w & 0xffff0000u);
}

// ---------------------------------------------------------------------------
// convert3: fp32 -> bf16 for x, w_qkv, w_out (unchanged)
// ---------------------------------------------------------------------------
#define XN8 (S_LEN * HID / 8)          // 524288
#define QN8 (QKV_O * HID / 8)          // 786432
#define ON8 (HID * HID / 8)            // 524288

__global__ __launch_bounds__(256) void convert3(
    const float* __restrict__ x, const float* __restrict__ wq,
    const float* __restrict__ wo, ushort_t* __restrict__ xb,
    ushort_t* __restrict__ wqb, ushort_t* __restrict__ wob) {
    int i = blockIdx.x * 256 + threadIdx.x;
    const float* s; ushort_t* d; int off;
    if (i < XN8)            { s = x;  d = xb;  off = i; }
    else if (i < XN8 + QN8) { s = wq; d = wqb; off = i - XN8; }
    else                    { s = wo; d = wob; off = i - XN8 - QN8; }
    const float4* sp = (const float4*)s + (size_t)off * 2;
    float4 a = sp[0], b = sp[1];
    *(uint4*)(d + (size_t)off * 8) = make_uint4(
        pk_bf16(a.x, a.y), pk_bf16(a.z, a.w),
        pk_bf16(b.x, b.y), pk_bf16(b.z, b.w));
}

// ---------------------------------------------------------------------------
// gemm_bk64: pure-bf16 GEMM, 64x128 tile, BK=64, XOR-swizzled LDS, dbuf,
// __syncthreads per k-step (round-6 proven form). Counted-vmcnt abandoned
// (raced r7; regime-gate says NULL at 2-phase anyway).
// ROPE: fused in-lane RoPE epilogue for q/k tiles (bn < V_COL).
// VT:   V tiles (bn >= V_COL) stored transposed to VtG[vcol][seq].
// ---------------------------------------------------------------------------
template<bool CF32, bool ROPE, bool VT>
__global__ __launch_bounds__(256, 3) void gemm_bk64(
    const ushort_t* __restrict__ A, const ushort_t* __restrict__ Bt,
    void* __restrict__ Cp, int M, int N, int K,
    const float* __restrict__ cs, const float* __restrict__ sn,
    ushort_t* __restrict__ VtG) {
    __shared__ ushort_t As[2][64][64];     // 16 KB
    __shared__ ushort_t Bs[2][128][64];    // 32 KB

    const int t    = threadIdx.x;
    const int wave = t >> 6;
    const int lane = t & 63;
    const int quad = lane >> 4;
    const int l16  = lane & 15;
    const int wm   = (wave >> 1) << 5;
    const int wn   = (wave & 1)  << 6;
    const int bm   = blockIdx.y * 64;
    const int bn   = blockIdx.x * 128;
    const int lr   = lane >> 3;
    const int lc   = ((lane & 7) ^ lr) << 3;

    f32x4 acc[2][4];
    #pragma unroll
    for (int i = 0; i < 2; i++)
        #pragma unroll
        for (int j = 0; j < 4; j++) {
            f32x4 z = {0.f, 0.f, 0.f, 0.f};
            acc[i][j] = z;
        }

    const ushort_t* a0 = &A[(size_t)(bm + wave * 16 + lr) * K + lc];
    const ushort_t* b0 = &Bt[(size_t)(bn + wave * 32 + lr) * K + lc];
    const size_t r8 = (size_t)8 * K;

    // ---- prologue: stage k=0 into buffer 0 ----
    __builtin_amdgcn_global_load_lds(GLB(a0),          LDSP(&As[0][wave * 16][0]),      16, 0, 0);
    __builtin_amdgcn_global_load_lds(GLB(a0 + r8),     LDSP(&As[0][wave * 16 + 8][0]),  16, 0, 0);
    __builtin_amdgcn_global_load_lds(GLB(b0),          LDSP(&Bs[0][wave * 32][0]),      16, 0, 0);
    __builtin_amdgcn_global_load_lds(GLB(b0 + r8),     LDSP(&Bs[0][wave * 32 + 8][0]),  16, 0, 0);
    __builtin_amdgcn_global_load_lds(GLB(b0 + 2 * r8), LDSP(&Bs[0][wave * 32 + 16][0]), 16, 0, 0);
    __builtin_amdgcn_global_load_lds(GLB(b0 + 3 * r8), LDSP(&Bs[0][wave * 32 + 24][0]), 16, 0, 0);
    __syncthreads();

    const int nk = K >> 6;
    for (int kk = 0; kk < nk; kk++) {
        const int cur = kk & 1, nxt = cur ^ 1;

        // ---- issue DMA for k+1 into the alternate buffer (flies under MFMA)
        if (kk + 1 < nk) {
            const int k0 = (kk + 1) << 6;
            __builtin_amdgcn_global_load_lds(GLB(a0 + k0),          LDSP(&As[nxt][wave * 16][0]),      16, 0, 0);
            __builtin_amdgcn_global_load_lds(GLB(a0 + k0 + r8),     LDSP(&As[nxt][wave * 16 + 8][0]),  16, 0, 0);
            __builtin_amdgcn_global_load_lds(GLB(b0 + k0),          LDSP(&Bs[nxt][wave * 32][0]),      16, 0, 0);
            __builtin_amdgcn_global_load_lds(GLB(b0 + k0 + r8),     LDSP(&Bs[nxt][wave * 32 + 8][0]),  16, 0, 0);
            __builtin_amdgcn_global_load_lds(GLB(b0 + k0 + 2 * r8), LDSP(&Bs[nxt][wave * 32 + 16][0]), 16, 0, 0);
            __builtin_amdgcn_global_load_lds(GLB(b0 + k0 + 3 * r8), LDSP(&Bs[nxt][wave * 32 + 24][0]), 16, 0, 0);
        }

        // ---- compute current buffer ----
        #pragma unroll
        for (int ks = 0; ks < 2; ks++) {
            const int ca = (((ks << 2) + quad) ^ (l16 & 7)) << 3;
            bf16x8 af[2], bfr[4];
            #pragma unroll
            for (int i = 0; i < 2; i++)
                af[i] = *(const bf16x8*)&As[cur][wm + i * 16 + l16][ca];
            #pragma unroll
            for (int j = 0; j < 4; j++)
                bfr[j] = *(const bf16x8*)&Bs[cur][wn + j * 16 + l16][ca];

            #pragma unroll
            for (int i = 0; i < 2; i++)
                #pragma unroll
                for (int j = 0; j < 4; j++)
                    acc[i][j] = __builtin_amdgcn_mfma_f32_16x16x32_bf16(
                        af[i], bfr[j], acc[i][j], 0, 0, 0);
        }
        __syncthreads();   // one barrier/k-step; drains vmcnt -> buf[nxt] ready
    }

    // Epilogue: C/D layout col=lane&15 (+nd*16), row=quad*4+reg
    if (ROPE && bn < V_COL) {
        #pragma unroll
        for (int i = 0; i < 2; i++)
            #pragma unroll
            for (int r = 0; r < 4; r++) {
                const int srow = bm + wm + i * 16 + quad * 4 + r;
                float cv[4], sv[4], o[4];
                #pragma unroll
                for (int nd = 0; nd < 4; nd++) {
                    const int d = nd * 16 + l16;
                    cv[nd] = cs[srow * HD + d];
                    sv[nd] = sn[srow * HD + d];
                }
                o[0] = acc[i][0][r] * cv[0] - acc[i][2][r] * sv[0];
                o[1] = acc[i][1][r] * cv[1] - acc[i][3][r] * sv[1];
                o[2] = acc[i][2][r] * cv[2] + acc[i][0][r] * sv[2];
                o[3] = acc[i][3][r] * cv[3] + acc[i][1][r] * sv[3];
                #pragma unroll
                for (int nd = 0; nd < 4; nd++) {
                    const int col = bn + wn + nd * 16 + l16;
                    ((ushort_t*)Cp)[(size_t)srow * N + col] = f2bf(o[nd]);
                }
            }
    } else if (VT && bn >= V_COL) {
        #pragma unroll
        for (int i = 0; i < 2; i++) {
            const int srow0 = bm + wm + i * 16 + quad * 4;
            #pragma unroll
            for (int nd = 0; nd < 4; nd++) {
                const int vcol = bn + wn + nd * 16 + l16 - V_COL;
                uint2 w2 = make_uint2(
                    pk_bf16(acc[i][nd][0], acc[i][nd][1]),
                    pk_bf16(acc[i][nd][2], acc[i][nd][3]));
                *(uint2*)&VtG[(size_t)vcol * S_LEN + srow0] = w2;
            }
        }
    } else {
        #pragma unroll
        for (int i = 0; i < 2; i++)
            #pragma unroll
            for (int j = 0; j < 4; j++)
                #pragma unroll
                for (int r = 0; r < 4; r++) {
                    int row = bm + wm + i * 16 + quad * 4 + r;
                    int col = bn + wn + j * 16 + l16;
                    if (CF32)
                        ((float*)Cp)[(size_t)row * N + col] = acc[i][j][r];
                    else
                        ((ushort_t*)Cp)[(size_t)row * N + col] = f2bf(acc[i][j][r]);
                }
    }
}

// ---------------------------------------------------------------------------
// Fallback GEMM with fused fp32->bf16 staging (small-ws path; unchanged)
// ---------------------------------------------------------------------------
template<bool AF32, bool BF32, bool CF32>
__global__ __launch_bounds__(256) void gemm_bt(
    const void* __restrict__ Ap, const void* __restrict__ Bp,
    void* __restrict__ Cp, int M, int N, int K) {
    __shared__ ushort_t As[128][40];
    __shared__ ushort_t Bs[128][40];

    const int t    = threadIdx.x;
    const int wave = t >> 6;
    const int lane = t & 63;
    const int quad = lane >> 4;
    const int l16  = lane & 15;
    const int wm   = (wave >> 1) << 6;
    const int wn   = (wave & 1)  << 6;
    const int bm   = blockIdx.y * 128;
    const int bn   = blockIdx.x * 128;
    const int sr   = t >> 2;
    const int sc   = (t & 3) << 3;

    f32x4 acc[4][4];
    #pragma unroll
    for (int i = 0; i < 4; i++)
        #pragma unroll
        for (int j = 0; j < 4; j++) {
            f32x4 z = {0.f, 0.f, 0.f, 0.f};
            acc[i][j] = z;
        }

    for (int k0 = 0; k0 < K; k0 += 32) {
        __syncthreads();
        if (AF32) {
            const float* A = (const float*)Ap;
            const float* p0 = &A[(size_t)(bm + sr) * K + k0 + sc];
            const float* p1 = &A[(size_t)(bm + sr + 64) * K + k0 + sc];
            float4 a0 = *(const float4*)p0, a1 = *(const float4*)(p0 + 4);
            float4 b0 = *(const float4*)p1, b1 = *(const float4*)(p1 + 4);
            *(uint4*)&As[sr][sc] = make_uint4(
                pk_bf16(a0.x, a0.y), pk_bf16(a0.z, a0.w),
                pk_bf16(a1.x, a1.y), pk_bf16(a1.z, a1.w));
            *(uint4*)&As[sr + 64][sc] = make_uint4(
                pk_bf16(b0.x, b0.y), pk_bf16(b0.z, b0.w),
                pk_bf16(b1.x, b1.y), pk_bf16(b1.z, b1.w));
        } else {
            const ushort_t* A = (const ushort_t*)Ap;
            *(uint4*)&As[sr][sc]      = *(const uint4*)&A[(size_t)(bm + sr) * K + k0 + sc];
            *(uint4*)&As[sr + 64][sc] = *(const uint4*)&A[(size_t)(bm + sr + 64) * K + k0 + sc];
        }
        if (BF32) {
            const float* B = (const float*)Bp;
            const float* p0 = &B[(size_t)(bn + sr) * K + k0 + sc];
            const float* p1 = &B[(size_t)(bn + sr + 64) * K + k0 + sc];
            float4 a0 = *(const float4*)p0, a1 = *(const float4*)(p0 + 4);
            float4 b0 = *(const float4*)p1, b1 = *(const float4*)(p1 + 4);
            *(uint4*)&Bs[sr][sc] = make_uint4(
                pk_bf16(a0.x, a0.y), pk_bf16(a0.z, a0.w),
                pk_bf16(a1.x, a1.y), pk_bf16(a1.z, a1.w));
            *(uint4*)&Bs[sr + 64][sc] = make_uint4(
                pk_bf16(b0.x, b0.y), pk_bf16(b0.z, b0.w),
                pk_bf16(b1.x, b1.y), pk_bf16(b1.z, b1.w));
        } else {
            const ushort_t* B = (const ushort_t*)Bp;
            *(uint4*)&Bs[sr][sc]      = *(const uint4*)&B[(size_t)(bn + sr) * K + k0 + sc];
            *(uint4*)&Bs[sr + 64][sc] = *(const uint4*)&B[(size_t)(bn + sr + 64) * K + k0 + sc];
        }
        __syncthreads();

        bf16x8 af[4], bfr[4];
        #pragma unroll
        for (int i = 0; i < 4; i++)
            af[i] = *(const bf16x8*)&As[wm + i * 16 + l16][quad * 8];
        #pragma unroll
        for (int j = 0; j < 4; j++)
            bfr[j] = *(const bf16x8*)&Bs[wn + j * 16 + l16][quad * 8];

        #pragma unroll
        for (int i = 0; i < 4; i++)
            #pragma unroll
            for (int j = 0; j < 4; j++)
                acc[i][j] = __builtin_amdgcn_mfma_f32_16x16x32_bf16(
                    af[i], bfr[j], acc[i][j], 0, 0, 0);
    }

    #pragma unroll
    for (int i = 0; i < 4; i++)
        #pragma unroll
        for (int j = 0; j < 4; j++)
            #pragma unroll
            for (int r = 0; r < 4; r++) {
                int row = bm + wm + i * 16 + quad * 4 + r;
                int col = bn + wn + j * 16 + l16;
                if (CF32)
                    ((float*)Cp)[(size_t)row * N + col] = acc[i][j][r];
                else
                    ((ushort_t*)Cp)[(size_t)row * N + col] = f2bf(acc[i][j][r]);
            }
}

// ---------------------------------------------------------------------------
// RoPE standalone (fallback path only)
// ---------------------------------------------------------------------------
__global__ __launch_bounds__(256) void rope_kernel(
    ushort_t* __restrict__ qkv, const float* __restrict__ cs,
    const float* __restrict__ sn) {
    int idx = blockIdx.x * 256 + threadIdx.x;
    if (idx >= S_LEN * (NQH + NKVH)) return;
    int s  = idx / (NQH + NKVH);
    int hh = idx - s * (NQH + NKVH);

    ushort_t* p = &qkv[(size_t)s * QKV_O + hh * HD];
    const uint4* p4 = (const uint4*)p;
    float v[HD], c[HD], sv[HD];
    #pragma unroll
    for (int b = 0; b < 8; b++) unpack8(&v[b * 8], p4[b]);
    const float4* c4 = (const float4*)&cs[s * HD];
    const float4* s4 = (const float4*)&sn[s * HD];
    #pragma unroll
    for (int b = 0; b < 16; b++) {
        ((float4*)c)[b]  = c4[b];
        ((float4*)sv)[b] = s4[b];
    }
    float o[HD];
    #pragma unroll
    for (int d = 0; d < 32; d++) {
        o[d]      = v[d] * c[d]           - v[d + 32] * sv[d];
        o[d + 32] = v[d + 32] * c[d + 32] + v[d]      * sv[d + 32];
    }
    unsigned int* pw = (unsigned int*)p;
    #pragma unroll
    for (int d = 0; d < HD; d += 2)
        pw[d >> 1] = pk_bf16(o[d], o[d + 1]);
}

// ---------------------------------------------------------------------------
// attn_v5: round-12/13 kernel (fallback paths; reads V from qkv)
// ---------------------------------------------------------------------------
__global__ __launch_bounds__(256) void attn_v5(
    const ushort_t* __restrict__ qkv, ushort_t* __restrict__ O) {
    const int bx   = blockIdx.x;
    const int h    = bx & 31;
    const int p    = bx >> 5;
    const int kvh  = h >> 2;
    const int q0d  = (31 - p) * 64;
    const int q0s  = p * 64;
    const int tid  = threadIdx.x;
    const int wave = tid >> 6;
    const int lane = tid & 63;
    const int quad = lane >> 4;
    const int l16  = lane & 15;

    __shared__ __align__(16) ushort_t Ks[2][64][72];
    __shared__ __align__(16) ushort_t Vt[2][64][72];
    __shared__ __align__(16) ushort_t Pl[4][32][72];

    const int rowbase0 = q0d + wave * 16;
    const int rowbase1 = q0s + wave * 16;

    bf16x8 bq[2][2];
    #pragma unroll
    for (int mi = 0; mi < 2; mi++) {
        const int rb = (mi == 0) ? rowbase0 : rowbase1;
        #pragma unroll
        for (int ks = 0; ks < 2; ks++) {
            uint4 u = *(const uint4*)&qkv[(size_t)(rb + l16) * QKV_O
                                          + h * HD + ks * 32 + quad * 8];
            float f[8]; unpack8(f, u);
            uint4 w = make_uint4(
                pk_bf16(f[0] * 0.125f, f[1] * 0.125f),
                pk_bf16(f[2] * 0.125f, f[3] * 0.125f),
                pk_bf16(f[4] * 0.125f, f[5] * 0.125f),
                pk_bf16(f[6] * 0.125f, f[7] * 0.125f));
            __builtin_memcpy(&bq[mi][ks], &w, 16);
        }
    }

    bf16x8 ones;
    #pragma unroll
    for (int e = 0; e < 8; e++) ones[e] = (__bf16)1.0f;

    f32x4 acc_o[2][4];
    f32x4 acc_l[2];
    #pragma unroll
    for (int mi = 0; mi < 2; mi++) {
        f32x4 z = {0.f, 0.f, 0.f, 0.f};
        acc_l[mi] = z;
        #pragma unroll
        for (int n = 0; n < 4; n++) acc_o[mi][n] = z;
    }

    const int nt = 32 - p;
    const int sr = tid >> 2;
    const int sc = (tid & 3) << 4;

    {
        const ushort_t* kp = &qkv[(size_t)sr * QKV_O + K_COL + kvh * HD + sc];
        *(uint4*)&Ks[0][sr][sc]     = *(const uint4*)kp;
        *(uint4*)&Ks[0][sr][sc + 8] = *(const uint4*)(kp + 8);
        const ushort_t* vp = &qkv[(size_t)sr * QKV_O + V_COL + kvh * HD + sc];
        ushort_t tmp[16];
        *(uint4*)&tmp[0] = *(const uint4*)vp;
        *(uint4*)&tmp[8] = *(const uint4*)(vp + 8);
        #pragma unroll
        for (int e = 0; e < 16; e++) {
            int d = sc + e;
            Vt[0][d][(sr + 8 * (d >> 3)) & 63] = tmp[e];
        }
    }
    __syncthreads();

    for (int t = 0; t < nt; t++) {
        const int cur = t & 1, nxt = cur ^ 1;
        const int j0 = t * 64;
        const bool hasNext = (t + 1 < nt);

        uint4 ka, kb, va, vb;
        if (hasNext) {
            const size_t rbase = (size_t)(j0 + 64 + sr) * QKV_O;
            const ushort_t* kp = &qkv[rbase + K_COL + kvh * HD + sc];
            ka = *(const uint4*)kp; kb = *(const uint4*)(kp + 8);
            const ushort_t* vp = &qkv[rbase + V_COL + kvh * HD + sc];
            va = *(const uint4*)vp; vb = *(const uint4*)(vp + 8);
        }

        const bool sact = (t <= p);

        f32x4 st[2][4];
        #pragma unroll
        for (int mi = 0; mi < 2; mi++)
            #pragma unroll
            for (int nk = 0; nk < 4; nk++) {
                f32x4 z = {0.f, 0.f, 0.f, 0.f};
                st[mi][nk] = z;
            }
        #pragma unroll
        for (int ks = 0; ks < 2; ks++) {
            bf16x8 ak[4];
            #pragma unroll
            for (int nk = 0; nk < 4; nk++)
                ak[nk] = *(const bf16x8*)&Ks[cur][nk * 16 + l16][ks * 32 + quad * 8];
            #pragma unroll
            for (int mi = 0; mi < 2; mi++) {
                if (mi == 1 && !sact) continue;
                #pragma unroll
                for (int nk = 0; nk < 4; nk++)
                    st[mi][nk] = __builtin_amdgcn_mfma_f32_16x16x32_bf16(
                        ak[nk], bq[mi][ks], st[mi][nk], 0, 0, 0);
            }
        }

        #pragma unroll
        for (int mi = 0; mi < 2; mi++) {
            if (mi == 1 && !sact) continue;
            const bool diag = (mi == 0) ? (t == nt - 1) : (t == p);
            const int qrow = ((mi == 0) ? rowbase0 : rowbase1) + l16;
            #pragma unroll
            for (int nk = 0; nk < 4; nk++) {
                const int kc0 = j0 + nk * 16 + quad * 4;
                float pv[4];
                #pragma unroll
                for (int r = 0; r < 4; r++) {
                    float e = __expf(st[mi][nk][r]);
                    pv[r] = (diag && (kc0 + r > qrow)) ? 0.f : e;
                }
                uint2 w2 = make_uint2(pk_bf16(pv[0], pv[1]), pk_bf16(pv[2], pv[3]));
                *(uint2*)&Pl[wave][mi * 16 + l16][nk * 16 + quad * 4] = w2;
            }
        }

        #pragma unroll
        for (int ksp = 0; ksp < 2; ksp++) {
            bf16x8 bv[4];
            #pragma unroll
            for (int nd = 0; nd < 4; nd++) {
                const int d = nd * 16 + l16;
                bv[nd] = *(const bf16x8*)&Vt[cur][d][(ksp * 32 + quad * 8 + 8 * (d >> 3)) & 63];
            }
            #pragma unroll
            for (int mi = 0; mi < 2; mi++) {
                if (mi == 1 && !sact) continue;
                bf16x8 ap = *(const bf16x8*)&Pl[wave][mi * 16 + l16][ksp * 32 + quad * 8];
                acc_l[mi] = __builtin_amdgcn_mfma_f32_16x16x32_bf16(
                    ap, ones, acc_l[mi], 0, 0, 0);
                #pragma unroll
                for (int nd = 0; nd < 4; nd++)
                    acc_o[mi][nd] = __builtin_amdgcn_mfma_f32_16x16x32_bf16(
                        ap, bv[nd], acc_o[mi][nd], 0, 0, 0);
            }
        }

        if (hasNext) {
            *(uint4*)&Ks[nxt][sr][sc]     = ka;
            *(uint4*)&Ks[nxt][sr][sc + 8] = kb;
            ushort_t tmp[16];
            *(uint4*)&tmp[0] = va;
            *(uint4*)&tmp[8] = vb;
            #pragma unroll
            for (int e = 0; e < 16; e++) {
                int d = sc + e;
                Vt[nxt][d][(sr + 8 * (d >> 3)) & 63] = tmp[e];
            }
        }
        __syncthreads();
    }

    #pragma unroll
    for (int mi = 0; mi < 2; mi++) {
        const int rb = (mi == 0) ? rowbase0 : rowbase1;
        float inv[4];
        #pragma unroll
        for (int r = 0; r < 4; r++) inv[r] = 1.0f / acc_l[mi][r];
        #pragma unroll
        for (int nd = 0; nd < 4; nd++)
            #pragma unroll
            for (int r = 0; r < 4; r++) {
                int row = rb + quad * 4 + r;
                int col = h * HD + nd * 16 + l16;
                O[(size_t)row * (NQH * HD) + col] = f2bf(acc_o[mi][nd][r] * inv[r]);
            }
    }
}

// ---------------------------------------------------------------------------
// attn_v8 (round-12 revision, resubmitted unchanged after container infra
// failure): Pl shrunk 9 KB -> 8 KB by replacing the +8 row padding with the
// XOR swizzle (col ^= (l16&7)<<3; same row -> same XOR on write and read,
// pure layout identity). Total LDS = 16+16+8 = 40 KB exactly -> 4 blocks/CU
// (4 x 40960 = 163840 = full LDS), whole 1024-block grid co-resident from
// t=0 (no dispatch tail; per-CU work exactly 66 tiles under the bz mapping).
// setprio (round-11, +1us measured) retained.
// ---------------------------------------------------------------------------
__global__ __launch_bounds__(256, 4) void attn_v8(
    const ushort_t* __restrict__ qkv, const ushort_t* __restrict__ VtG,
    ushort_t* __restrict__ O) {
    const int bx   = blockIdx.x;            // 1024 blocks
    const int h    = bx & 31;
    const int bz   = bx >> 5;               // 0..31
    const int qi   = (bz < 16) ? (31 - bz) : (bz - 16);
    const int kvh  = h >> 2;
    const int q0   = qi * 64;
    const int tid  = threadIdx.x;
    const int wave = tid >> 6;              // 0..3
    const int lane = tid & 63;
    const int quad = lane >> 4;
    const int l16  = lane & 15;

    __shared__ __align__(16) ushort_t Ks[2][64][64];   // 16 KB (DMA, swizzled)
    __shared__ __align__(16) ushort_t Vt[2][64][64];   // 16 KB (DMA, swizzled)
    __shared__ __align__(16) ushort_t Pl[4][16][64];   // 8 KB (XOR-swizzled)

    const int rb = q0 + wave * 16;          // this wave's 16 q-rows
    const int nt = qi + 1;                  // diag tile == last tile, all waves
    const int psw = (l16 & 7) << 3;         // Pl XOR swizzle (row-derived)

    // Q B-frags (lane l16 = qrow), pre-scaled by (1/8)*log2(e) for exp2
    bf16x8 bq[2];
    #pragma unroll
    for (int ks = 0; ks < 2; ks++) {
        uint4 u = *(const uint4*)&qkv[(size_t)(rb + l16) * QKV_O
                                      + h * HD + ks * 32 + quad * 8];
        float f[8]; unpack8(f, u);
        const float QS = 0.18033688011112042f;   // 0.125 * log2(e)
        uint4 w = make_uint4(
            pk_bf16(f[0] * QS, f[1] * QS), pk_bf16(f[2] * QS, f[3] * QS),
            pk_bf16(f[4] * QS, f[5] * QS), pk_bf16(f[6] * QS, f[7] * QS));
        __builtin_memcpy(&bq[ks], &w, 16);
    }

    bf16x8 ones;
    #pragma unroll
    for (int e = 0; e < 8; e++) ones[e] = (__bf16)1.0f;

    f32x4 acc_o[4];
    f32x4 acc_l;
    {
        f32x4 z = {0.f, 0.f, 0.f, 0.f};
        acc_l = z;
        #pragma unroll
        for (int n = 0; n < 4; n++) acc_o[n] = z;
    }

    // DMA lane geometry (XOR swizzle on the source side); wave stages 16 rows
    // of K and 16 rows of V^T per tile (2 x 1KB DMA ops each).
    const int lr = lane >> 3;                 // row-in-group 0..7
    const int cg = ((lane & 7) ^ lr) << 3;    // swizzled global chunk (elems)
    const ushort_t* kbase = &qkv[(size_t)(wave * 16 + lr) * QKV_O + K_COL + kvh * HD + cg];
    const size_t    kr8   = (size_t)8 * QKV_O;
    const ushort_t* vbase = &VtG[(size_t)(kvh * HD + wave * 16 + lr) * S_LEN + cg];
    const size_t    vr8   = (size_t)8 * S_LEN;

    // ---- prologue: DMA tile 0 -> buffer 0 ----
    __builtin_amdgcn_global_load_lds(GLB(kbase),       LDSP(&Ks[0][wave * 16][0]),     16, 0, 0);
    __builtin_amdgcn_global_load_lds(GLB(kbase + kr8), LDSP(&Ks[0][wave * 16 + 8][0]), 16, 0, 0);
    __builtin_amdgcn_global_load_lds(GLB(vbase),       LDSP(&Vt[0][wave * 16][0]),     16, 0, 0);
    __builtin_amdgcn_global_load_lds(GLB(vbase + vr8), LDSP(&Vt[0][wave * 16 + 8][0]), 16, 0, 0);
    __syncthreads();

    for (int t = 0; t < nt; t++) {
        const int cur = t & 1, nxt = cur ^ 1;
        const int j0 = t * 64;

        // ---- DMA-prefetch tile t+1 -> alternate buffer (flies during compute)
        if (t + 1 < nt) {
            const size_t kj = (size_t)(j0 + 64) * QKV_O;
            __builtin_amdgcn_global_load_lds(GLB(kbase + kj),             LDSP(&Ks[nxt][wave * 16][0]),     16, 0, 0);
            __builtin_amdgcn_global_load_lds(GLB(kbase + kj + kr8),       LDSP(&Ks[nxt][wave * 16 + 8][0]), 16, 0, 0);
            __builtin_amdgcn_global_load_lds(GLB(vbase + (j0 + 64)),      LDSP(&Vt[nxt][wave * 16][0]),     16, 0, 0);
            __builtin_amdgcn_global_load_lds(GLB(vbase + (j0 + 64) + vr8),LDSP(&Vt[nxt][wave * 16 + 8][0]), 16, 0, 0);
        }

        // ---- S^T = K·Q^T (setprio: favor MFMA-entering waves) ----
        f32x4 st[4];
        #pragma unroll
        for (int nk = 0; nk < 4; nk++) {
            f32x4 z = {0.f, 0.f, 0.f, 0.f};
            st[nk] = z;
        }
        __builtin_amdgcn_s_setprio(1);
        #pragma unroll
        for (int ks = 0; ks < 2; ks++) {
            const int ca = (((ks << 2) + quad) ^ (l16 & 7)) << 3;
            bf16x8 ak[4];
            #pragma unroll
            for (int nk = 0; nk < 4; nk++)
                ak[nk] = *(const bf16x8*)&Ks[cur][nk * 16 + l16][ca];
            #pragma unroll
            for (int nk = 0; nk < 4; nk++)
                st[nk] = __builtin_amdgcn_mfma_f32_16x16x32_bf16(
                    ak[nk], bq[ks], st[nk], 0, 0, 0);
        }
        __builtin_amdgcn_s_setprio(0);

        // ---- exp2 + causal mask (diag = last tile only), b64 P stores ----
        if (t == nt - 1) {
            const int qrow = rb + l16;
            #pragma unroll
            for (int nk = 0; nk < 4; nk++) {
                const int kc0 = j0 + nk * 16 + quad * 4;
                float pv[4];
                #pragma unroll
                for (int r = 0; r < 4; r++)
                    pv[r] = (kc0 + r > qrow) ? 0.f : exp2f(st[nk][r]);
                uint2 w2 = make_uint2(pk_bf16(pv[0], pv[1]), pk_bf16(pv[2], pv[3]));
                *(uint2*)&Pl[wave][l16][(nk * 16 + quad * 4) ^ psw] = w2;
            }
        } else {
            #pragma unroll
            for (int nk = 0; nk < 4; nk++) {
                float pv[4];
                #pragma unroll
                for (int r = 0; r < 4; r++)
                    pv[r] = exp2f(st[nk][r]);
                uint2 w2 = make_uint2(pk_bf16(pv[0], pv[1]), pk_bf16(pv[2], pv[3]));
                *(uint2*)&Pl[wave][l16][(nk * 16 + quad * 4) ^ psw] = w2;
            }
        }

        // ---- l += P·1 ; O += P·V (setprio around the MFMA cluster) ----
        __builtin_amdgcn_s_setprio(1);
        #pragma unroll
        for (int ksp = 0; ksp < 2; ksp++) {
            const int ca = (((ksp << 2) + quad) ^ (l16 & 7)) << 3;
            bf16x8 bv[4];
            #pragma unroll
            for (int nd = 0; nd < 4; nd++)
                bv[nd] = *(const bf16x8*)&Vt[cur][nd * 16 + l16][ca];
            bf16x8 ap = *(const bf16x8*)&Pl[wave][l16][(ksp * 32 + quad * 8) ^ psw];
            acc_l = __builtin_amdgcn_mfma_f32_16x16x32_bf16(
                ap, ones, acc_l, 0, 0, 0);
            #pragma unroll
            for (int nd = 0; nd < 4; nd++)
                acc_o[nd] = __builtin_amdgcn_mfma_f32_16x16x32_bf16(
                    ap, bv[nd], acc_o[nd], 0, 0, 0);
        }
        __builtin_amdgcn_s_setprio(0);
        __syncthreads();   // one barrier/tile; compiler drains vmcnt here
    }

    // ---- epilogue: O / l ----
    float inv[4];
    #pragma unroll
    for (int r = 0; r < 4; r++) inv[r] = 1.0f / acc_l[r];
    #pragma unroll
    for (int nd = 0; nd < 4; nd++)
        #pragma unroll
        for (int r = 0; r < 4; r++) {
            int row = rb + quad * 4 + r;
            int col = h * HD + nd * 16 + l16;
            O[(size_t)row * (NQH * HD) + col] = f2bf(acc_o[nd][r] * inv[r]);
        }
}

// ---------------------------------------------------------------------------
extern "C" void kernel_launch(void* const* d_in, const int* in_sizes, int n_in,
                              void* d_out, int out_size, void* d_ws, size_t ws_size,
                              hipStream_t stream) {
    const float* x     = (const float*)d_in[0];  // [2048][2048] fp32
    const float* cosp  = (const float*)d_in[1];  // [2048][64]   fp32
    const float* sinp  = (const float*)d_in[2];  // [2048][64]   fp32
    const float* w_qkv = (const float*)d_in[3];  // [3072][2048] fp32
    const float* w_out = (const float*)d_in[4];  // [2048][2048] fp32
    float* out = (float*)d_out;                  // [2048][2048] fp32

    const size_t NQKV = (size_t)S_LEN * QKV_O;   // 6291456
    const size_t NH2  = (size_t)S_LEN * HID;     // 4194304
    const size_t NVT  = (size_t)(NKVH * HD) * S_LEN;  // 1048576
    const size_t need_old = 2 * (NQKV + NH2) * sizeof(ushort_t);        // 41.9 MB
    const size_t need_new = need_old + NVT * sizeof(ushort_t);          // 44.0 MB

    ushort_t* qkv = (ushort_t*)d_ws;             // bf16 [2048][3072]
    ushort_t* x_bf    = qkv + NQKV;
    ushort_t* attnO   = x_bf;                    // disjoint lifetimes
    ushort_t* wqkv_bf = x_bf + NH2;
    ushort_t* wout_bf = wqkv_bf + NQKV;
    ushort_t* VtG     = wout_bf + NH2;           // bf16 [512][2048]

    if (ws_size >= need_new) {
        convert3<<<XN8 / 256 + QN8 / 256 + ON8 / 256, 256, 0, stream>>>(
            x, w_qkv, w_out, x_bf, wqkv_bf, wout_bf);

        // 1) qkv(q,k w/ RoPE) + VtG(V^T) = x @ w_qkv^T  (64x128, dbuf)
        dim3 g1(QKV_O / 128, S_LEN / 64);
        gemm_bk64<false, true, true><<<g1, 256, 0, stream>>>(
            x_bf, wqkv_bf, qkv, S_LEN, QKV_O, HID, cosp, sinp, VtG);

        // 2) causal GQA attention (v8 + setprio + 40KB LDS -> 4 blocks/CU)
        attn_v8<<<32 * NQH, 256, 0, stream>>>(qkv, VtG, attnO);

        // 3) out = attnO @ w_out^T  (64x128, dbuf)
        dim3 g2(HID / 128, S_LEN / 64);
        gemm_bk64<true, false, false><<<g2, 256, 0, stream>>>(
            attnO, wout_bf, out, S_LEN, HID, HID, nullptr, nullptr, nullptr);
    } else if (ws_size >= need_old) {
        // round-13 path (no VtG room)
        convert3<<<XN8 / 256 + QN8 / 256 + ON8 / 256, 256, 0, stream>>>(
            x, w_qkv, w_out, x_bf, wqkv_bf, wout_bf);

        dim3 g1(QKV_O / 128, S_LEN / 64);
        gemm_bk64<false, true, false><<<g1, 256, 0, stream>>>(
            x_bf, wqkv_bf, qkv, S_LEN, QKV_O, HID, cosp, sinp, nullptr);

        attn_v5<<<16 * NQH, 256, 0, stream>>>(qkv, attnO);

        dim3 g2(HID / 128, S_LEN / 64);
        gemm_bk64<true, false, false><<<g2, 256, 0, stream>>>(
            attnO, wout_bf, out, S_LEN, HID, HID, nullptr, nullptr, nullptr);
    } else {
        ushort_t* attnO2 = qkv + NQKV;

        dim3 g1(QKV_O / 128, S_LEN / 128);
        gemm_bt<true, true, false><<<g1, 256, 0, stream>>>(x, w_qkv, qkv, S_LEN, QKV_O, HID);

        int rope_threads = S_LEN * (NQH + NKVH);
        rope_kernel<<<(rope_threads + 255) / 256, 256, 0, stream>>>(qkv, cosp, sinp);

        attn_v5<<<16 * NQH, 256, 0, stream>>>(qkv, attnO2);

        dim3 g2(HID / 128, S_LEN / 128);
        gemm_bt<false, true, true><<<g2, 256, 0, stream>>>(attnO2, w_out, out, S_LEN, HID, HID);
    }
}

// Round 14
// 197.039 us; speedup vs baseline: 1.1138x; 1.0015x over previous
//
#include <hip/hip_runtime.h>
#include <hip/hip_bf16.h>
#include <stdint.h>

// Problem constants (B=1). I/O dtype: fp32. Internals bf16 (MFMA path).
#define S_LEN 2048
#define HID   2048
#define NQH   32
#define NKVH  8
#define HD    64
#define QKV_O 3072      // (32 + 2*8) * 64
#define K_COL 2048      // col offset of K block in qkv row
#define V_COL 2560      // col offset of V block in qkv row

typedef unsigned short ushort_t;
typedef __bf16 bf16x8 __attribute__((ext_vector_type(8)));
typedef float  f32x4  __attribute__((ext_vector_type(4)));

#define GLB(p) ((const __attribute__((address_space(1))) void*)(p))
#define LDSP(p) ((__attribute__((address_space(3))) void*)(p))

__device__ __forceinline__ ushort_t f2bf(float f) {
    unsigned int x = __float_as_uint(f);
    unsigned int r = (x + 0x7fffu + ((x >> 16) & 1u)) >> 16;   // RNE
    return (ushort_t)r;
}
__device__ __forceinline__ unsigned int pk_bf16(float a, float b) {
    __hip_bfloat162 h = __float22bfloat162_rn(make_float2(a, b));
    unsigned int r;
    __builtin_memcpy(&r, &h, 4);
    return r;
}
__device__ __forceinline__ void unpack8(float* dst, uint4 u) {
    dst[0] = __uint_as_float(u.x << 16); dst[1] = __uint_as_float(u.x & 0xffff0000u);
    dst[2] = __uint_as_float(u.y << 16); dst[3] = __uint_as_float(u.y & 0xffff0000u);
    dst[4] = __uint_as_float(u.z << 16); dst[5] = __uint_as_float(u.z & 0xffff0000u);
    dst[6] = __uint_as_float(u.w << 16); dst[7] = __uint_as_float(u.w & 0xffff0000u);
}

// ---------------------------------------------------------------------------
// convert3: fp32 -> bf16 for x, w_qkv, w_out (unchanged)
// ---------------------------------------------------------------------------
#define XN8 (S_LEN * HID / 8)          // 524288
#define QN8 (QKV_O * HID / 8)          // 786432
#define ON8 (HID * HID / 8)            // 524288

__global__ __launch_bounds__(256) void convert3(
    const float* __restrict__ x, const float* __restrict__ wq,
    const float* __restrict__ wo, ushort_t* __restrict__ xb,
    ushort_t* __restrict__ wqb, ushort_t* __restrict__ wob) {
    int i = blockIdx.x * 256 + threadIdx.x;
    const float* s; ushort_t* d; int off;
    if (i < XN8)            { s = x;  d = xb;  off = i; }
    else if (i < XN8 + QN8) { s = wq; d = wqb; off = i - XN8; }
    else                    { s = wo; d = wob; off = i - XN8 - QN8; }
    const float4* sp = (const float4*)s + (size_t)off * 2;
    float4 a = sp[0], b = sp[1];
    *(uint4*)(d + (size_t)off * 8) = make_uint4(
        pk_bf16(a.x, a.y), pk_bf16(a.z, a.w),
        pk_bf16(b.x, b.y), pk_bf16(b.z, b.w));
}

// ---------------------------------------------------------------------------
// gemm_bk64: pure-bf16 GEMM, 64x128 tile, BK=64, XOR-swizzled LDS, dbuf,
// __syncthreads per k-step (round-6 proven form). Used for gemm1 (768
// blocks = 3/CU, exactly the 48KB-LDS residency cap). ROPE epilogue needs
// the 128-wide BN (each wave spans a full 64-col head for in-lane
// rotate-half), so gemm1 stays on this shape.
// ROPE: fused in-lane RoPE epilogue for q/k tiles (bn < V_COL).
// VT:   V tiles (bn >= V_COL) stored transposed to VtG[vcol][seq].
// ---------------------------------------------------------------------------
template<bool CF32, bool ROPE, bool VT>
__global__ __launch_bounds__(256, 3) void gemm_bk64(
    const ushort_t* __restrict__ A, const ushort_t* __restrict__ Bt,
    void* __restrict__ Cp, int M, int N, int K,
    const float* __restrict__ cs, const float* __restrict__ sn,
    ushort_t* __restrict__ VtG) {
    __shared__ ushort_t As[2][64][64];     // 16 KB
    __shared__ ushort_t Bs[2][128][64];    // 32 KB

    const int t    = threadIdx.x;
    const int wave = t >> 6;
    const int lane = t & 63;
    const int quad = lane >> 4;
    const int l16  = lane & 15;
    const int wm   = (wave >> 1) << 5;
    const int wn   = (wave & 1)  << 6;
    const int bm   = blockIdx.y * 64;
    const int bn   = blockIdx.x * 128;
    const int lr   = lane >> 3;
    const int lc   = ((lane & 7) ^ lr) << 3;

    f32x4 acc[2][4];
    #pragma unroll
    for (int i = 0; i < 2; i++)
        #pragma unroll
        for (int j = 0; j < 4; j++) {
            f32x4 z = {0.f, 0.f, 0.f, 0.f};
            acc[i][j] = z;
        }

    const ushort_t* a0 = &A[(size_t)(bm + wave * 16 + lr) * K + lc];
    const ushort_t* b0 = &Bt[(size_t)(bn + wave * 32 + lr) * K + lc];
    const size_t r8 = (size_t)8 * K;

    // ---- prologue: stage k=0 into buffer 0 ----
    __builtin_amdgcn_global_load_lds(GLB(a0),          LDSP(&As[0][wave * 16][0]),      16, 0, 0);
    __builtin_amdgcn_global_load_lds(GLB(a0 + r8),     LDSP(&As[0][wave * 16 + 8][0]),  16, 0, 0);
    __builtin_amdgcn_global_load_lds(GLB(b0),          LDSP(&Bs[0][wave * 32][0]),      16, 0, 0);
    __builtin_amdgcn_global_load_lds(GLB(b0 + r8),     LDSP(&Bs[0][wave * 32 + 8][0]),  16, 0, 0);
    __builtin_amdgcn_global_load_lds(GLB(b0 + 2 * r8), LDSP(&Bs[0][wave * 32 + 16][0]), 16, 0, 0);
    __builtin_amdgcn_global_load_lds(GLB(b0 + 3 * r8), LDSP(&Bs[0][wave * 32 + 24][0]), 16, 0, 0);
    __syncthreads();

    const int nk = K >> 6;
    for (int kk = 0; kk < nk; kk++) {
        const int cur = kk & 1, nxt = cur ^ 1;

        // ---- issue DMA for k+1 into the alternate buffer (flies under MFMA)
        if (kk + 1 < nk) {
            const int k0 = (kk + 1) << 6;
            __builtin_amdgcn_global_load_lds(GLB(a0 + k0),          LDSP(&As[nxt][wave * 16][0]),      16, 0, 0);
            __builtin_amdgcn_global_load_lds(GLB(a0 + k0 + r8),     LDSP(&As[nxt][wave * 16 + 8][0]),  16, 0, 0);
            __builtin_amdgcn_global_load_lds(GLB(b0 + k0),          LDSP(&Bs[nxt][wave * 32][0]),      16, 0, 0);
            __builtin_amdgcn_global_load_lds(GLB(b0 + k0 + r8),     LDSP(&Bs[nxt][wave * 32 + 8][0]),  16, 0, 0);
            __builtin_amdgcn_global_load_lds(GLB(b0 + k0 + 2 * r8), LDSP(&Bs[nxt][wave * 32 + 16][0]), 16, 0, 0);
            __builtin_amdgcn_global_load_lds(GLB(b0 + k0 + 3 * r8), LDSP(&Bs[nxt][wave * 32 + 24][0]), 16, 0, 0);
        }

        // ---- compute current buffer ----
        #pragma unroll
        for (int ks = 0; ks < 2; ks++) {
            const int ca = (((ks << 2) + quad) ^ (l16 & 7)) << 3;
            bf16x8 af[2], bfr[4];
            #pragma unroll
            for (int i = 0; i < 2; i++)
                af[i] = *(const bf16x8*)&As[cur][wm + i * 16 + l16][ca];
            #pragma unroll
            for (int j = 0; j < 4; j++)
                bfr[j] = *(const bf16x8*)&Bs[cur][wn + j * 16 + l16][ca];

            #pragma unroll
            for (int i = 0; i < 2; i++)
                #pragma unroll
                for (int j = 0; j < 4; j++)
                    acc[i][j] = __builtin_amdgcn_mfma_f32_16x16x32_bf16(
                        af[i], bfr[j], acc[i][j], 0, 0, 0);
        }
        __syncthreads();   // one barrier/k-step; drains vmcnt -> buf[nxt] ready
    }

    // Epilogue: C/D layout col=lane&15 (+nd*16), row=quad*4+reg
    if (ROPE && bn < V_COL) {
        #pragma unroll
        for (int i = 0; i < 2; i++)
            #pragma unroll
            for (int r = 0; r < 4; r++) {
                const int srow = bm + wm + i * 16 + quad * 4 + r;
                float cv[4], sv[4], o[4];
                #pragma unroll
                for (int nd = 0; nd < 4; nd++) {
                    const int d = nd * 16 + l16;
                    cv[nd] = cs[srow * HD + d];
                    sv[nd] = sn[srow * HD + d];
                }
                o[0] = acc[i][0][r] * cv[0] - acc[i][2][r] * sv[0];
                o[1] = acc[i][1][r] * cv[1] - acc[i][3][r] * sv[1];
                o[2] = acc[i][2][r] * cv[2] + acc[i][0][r] * sv[2];
                o[3] = acc[i][3][r] * cv[3] + acc[i][1][r] * sv[3];
                #pragma unroll
                for (int nd = 0; nd < 4; nd++) {
                    const int col = bn + wn + nd * 16 + l16;
                    ((ushort_t*)Cp)[(size_t)srow * N + col] = f2bf(o[nd]);
                }
            }
    } else if (VT && bn >= V_COL) {
        #pragma unroll
        for (int i = 0; i < 2; i++) {
            const int srow0 = bm + wm + i * 16 + quad * 4;
            #pragma unroll
            for (int nd = 0; nd < 4; nd++) {
                const int vcol = bn + wn + nd * 16 + l16 - V_COL;
                uint2 w2 = make_uint2(
                    pk_bf16(acc[i][nd][0], acc[i][nd][1]),
                    pk_bf16(acc[i][nd][2], acc[i][nd][3]));
                *(uint2*)&VtG[(size_t)vcol * S_LEN + srow0] = w2;
            }
        }
    } else {
        #pragma unroll
        for (int i = 0; i < 2; i++)
            #pragma unroll
            for (int j = 0; j < 4; j++)
                #pragma unroll
                for (int r = 0; r < 4; r++) {
                    int row = bm + wm + i * 16 + quad * 4 + r;
                    int col = bn + wn + j * 16 + l16;
                    if (CF32)
                        ((float*)Cp)[(size_t)row * N + col] = acc[i][j][r];
                    else
                        ((ushort_t*)Cp)[(size_t)row * N + col] = f2bf(acc[i][j][r]);
                }
    }
}

// ---------------------------------------------------------------------------
// gemm_n64 (round-14): 64x64-tile variant for gemm2. gemm2's 64x128 grid was
// 512 blocks = 2 blocks/CU (8 waves/CU) — the most starved kernel in the
// pipeline. 64x64 -> grid (32,32) = 1024 blocks = 4/CU co-resident (LDS
// 16+16 = 32 KB -> 5 allowed). Same BK=64 dbuf template, same XOR swizzle,
// same k-accumulation order (bit-identical numerics). acc[2][2]/wave; each
// wave stages 16 rows of A and 16 rows of B per k-step (4 DMA). fp32 C out.
// ---------------------------------------------------------------------------
__global__ __launch_bounds__(256, 4) void gemm_n64(
    const ushort_t* __restrict__ A, const ushort_t* __restrict__ Bt,
    float* __restrict__ Cp, int M, int N, int K) {
    __shared__ ushort_t As[2][64][64];     // 16 KB
    __shared__ ushort_t Bs[2][64][64];     // 16 KB

    const int t    = threadIdx.x;
    const int wave = t >> 6;
    const int lane = t & 63;
    const int quad = lane >> 4;
    const int l16  = lane & 15;
    const int wm   = (wave >> 1) << 5;   // 0 / 32
    const int wn   = (wave & 1)  << 5;   // 0 / 32
    const int bm   = blockIdx.y * 64;
    const int bn   = blockIdx.x * 64;
    const int lr   = lane >> 3;
    const int lc   = ((lane & 7) ^ lr) << 3;

    f32x4 acc[2][2];
    #pragma unroll
    for (int i = 0; i < 2; i++)
        #pragma unroll
        for (int j = 0; j < 2; j++) {
            f32x4 z = {0.f, 0.f, 0.f, 0.f};
            acc[i][j] = z;
        }

    const ushort_t* a0 = &A[(size_t)(bm + wave * 16 + lr) * K + lc];
    const ushort_t* b0 = &Bt[(size_t)(bn + wave * 16 + lr) * K + lc];
    const size_t r8 = (size_t)8 * K;

    // ---- prologue: stage k=0 into buffer 0 ----
    __builtin_amdgcn_global_load_lds(GLB(a0),      LDSP(&As[0][wave * 16][0]),     16, 0, 0);
    __builtin_amdgcn_global_load_lds(GLB(a0 + r8), LDSP(&As[0][wave * 16 + 8][0]), 16, 0, 0);
    __builtin_amdgcn_global_load_lds(GLB(b0),      LDSP(&Bs[0][wave * 16][0]),     16, 0, 0);
    __builtin_amdgcn_global_load_lds(GLB(b0 + r8), LDSP(&Bs[0][wave * 16 + 8][0]), 16, 0, 0);
    __syncthreads();

    const int nk = K >> 6;
    for (int kk = 0; kk < nk; kk++) {
        const int cur = kk & 1, nxt = cur ^ 1;

        // ---- issue DMA for k+1 into the alternate buffer (flies under MFMA)
        if (kk + 1 < nk) {
            const int k0 = (kk + 1) << 6;
            __builtin_amdgcn_global_load_lds(GLB(a0 + k0),      LDSP(&As[nxt][wave * 16][0]),     16, 0, 0);
            __builtin_amdgcn_global_load_lds(GLB(a0 + k0 + r8), LDSP(&As[nxt][wave * 16 + 8][0]), 16, 0, 0);
            __builtin_amdgcn_global_load_lds(GLB(b0 + k0),      LDSP(&Bs[nxt][wave * 16][0]),     16, 0, 0);
            __builtin_amdgcn_global_load_lds(GLB(b0 + k0 + r8), LDSP(&Bs[nxt][wave * 16 + 8][0]), 16, 0, 0);
        }

        // ---- compute current buffer ----
        #pragma unroll
        for (int ks = 0; ks < 2; ks++) {
            const int ca = (((ks << 2) + quad) ^ (l16 & 7)) << 3;
            bf16x8 af[2], bfr[2];
            #pragma unroll
            for (int i = 0; i < 2; i++)
                af[i] = *(const bf16x8*)&As[cur][wm + i * 16 + l16][ca];
            #pragma unroll
            for (int j = 0; j < 2; j++)
                bfr[j] = *(const bf16x8*)&Bs[cur][wn + j * 16 + l16][ca];

            #pragma unroll
            for (int i = 0; i < 2; i++)
                #pragma unroll
                for (int j = 0; j < 2; j++)
                    acc[i][j] = __builtin_amdgcn_mfma_f32_16x16x32_bf16(
                        af[i], bfr[j], acc[i][j], 0, 0, 0);
        }
        __syncthreads();   // one barrier/k-step
    }

    // Epilogue: fp32 C store. C/D layout col=lane&15 (+j*16), row=quad*4+reg
    #pragma unroll
    for (int i = 0; i < 2; i++)
        #pragma unroll
        for (int j = 0; j < 2; j++)
            #pragma unroll
            for (int r = 0; r < 4; r++) {
                int row = bm + wm + i * 16 + quad * 4 + r;
                int col = bn + wn + j * 16 + l16;
                Cp[(size_t)row * N + col] = acc[i][j][r];
            }
}

// ---------------------------------------------------------------------------
// Fallback GEMM with fused fp32->bf16 staging (small-ws path; unchanged)
// ---------------------------------------------------------------------------
template<bool AF32, bool BF32, bool CF32>
__global__ __launch_bounds__(256) void gemm_bt(
    const void* __restrict__ Ap, const void* __restrict__ Bp,
    void* __restrict__ Cp, int M, int N, int K) {
    __shared__ ushort_t As[128][40];
    __shared__ ushort_t Bs[128][40];

    const int t    = threadIdx.x;
    const int wave = t >> 6;
    const int lane = t & 63;
    const int quad = lane >> 4;
    const int l16  = lane & 15;
    const int wm   = (wave >> 1) << 6;
    const int wn   = (wave & 1)  << 6;
    const int bm   = blockIdx.y * 128;
    const int bn   = blockIdx.x * 128;
    const int sr   = t >> 2;
    const int sc   = (t & 3) << 3;

    f32x4 acc[4][4];
    #pragma unroll
    for (int i = 0; i < 4; i++)
        #pragma unroll
        for (int j = 0; j < 4; j++) {
            f32x4 z = {0.f, 0.f, 0.f, 0.f};
            acc[i][j] = z;
        }

    for (int k0 = 0; k0 < K; k0 += 32) {
        __syncthreads();
        if (AF32) {
            const float* A = (const float*)Ap;
            const float* p0 = &A[(size_t)(bm + sr) * K + k0 + sc];
            const float* p1 = &A[(size_t)(bm + sr + 64) * K + k0 + sc];
            float4 a0 = *(const float4*)p0, a1 = *(const float4*)(p0 + 4);
            float4 b0 = *(const float4*)p1, b1 = *(const float4*)(p1 + 4);
            *(uint4*)&As[sr][sc] = make_uint4(
                pk_bf16(a0.x, a0.y), pk_bf16(a0.z, a0.w),
                pk_bf16(a1.x, a1.y), pk_bf16(a1.z, a1.w));
            *(uint4*)&As[sr + 64][sc] = make_uint4(
                pk_bf16(b0.x, b0.y), pk_bf16(b0.z, b0.w),
                pk_bf16(b1.x, b1.y), pk_bf16(b1.z, b1.w));
        } else {
            const ushort_t* A = (const ushort_t*)Ap;
            *(uint4*)&As[sr][sc]      = *(const uint4*)&A[(size_t)(bm + sr) * K + k0 + sc];
            *(uint4*)&As[sr + 64][sc] = *(const uint4*)&A[(size_t)(bm + sr + 64) * K + k0 + sc];
        }
        if (BF32) {
            const float* B = (const float*)Bp;
            const float* p0 = &B[(size_t)(bn + sr) * K + k0 + sc];
            const float* p1 = &B[(size_t)(bn + sr + 64) * K + k0 + sc];
            float4 a0 = *(const float4*)p0, a1 = *(const float4*)(p0 + 4);
            float4 b0 = *(const float4*)p1, b1 = *(const float4*)(p1 + 4);
            *(uint4*)&Bs[sr][sc] = make_uint4(
                pk_bf16(a0.x, a0.y), pk_bf16(a0.z, a0.w),
                pk_bf16(a1.x, a1.y), pk_bf16(a1.z, a1.w));
            *(uint4*)&Bs[sr + 64][sc] = make_uint4(
                pk_bf16(b0.x, b0.y), pk_bf16(b0.z, b0.w),
                pk_bf16(b1.x, b1.y), pk_bf16(b1.z, b1.w));
        } else {
            const ushort_t* B = (const ushort_t*)Bp;
            *(uint4*)&Bs[sr][sc]      = *(const uint4*)&B[(size_t)(bn + sr) * K + k0 + sc];
            *(uint4*)&Bs[sr + 64][sc] = *(const uint4*)&B[(size_t)(bn + sr + 64) * K + k0 + sc];
        }
        __syncthreads();

        bf16x8 af[4], bfr[4];
        #pragma unroll
        for (int i = 0; i < 4; i++)
            af[i] = *(const bf16x8*)&As[wm + i * 16 + l16][quad * 8];
        #pragma unroll
        for (int j = 0; j < 4; j++)
            bfr[j] = *(const bf16x8*)&Bs[wn + j * 16 + l16][quad * 8];

        #pragma unroll
        for (int i = 0; i < 4; i++)
            #pragma unroll
            for (int j = 0; j < 4; j++)
                acc[i][j] = __builtin_amdgcn_mfma_f32_16x16x32_bf16(
                    af[i], bfr[j], acc[i][j], 0, 0, 0);
    }

    #pragma unroll
    for (int i = 0; i < 4; i++)
        #pragma unroll
        for (int j = 0; j < 4; j++)
            #pragma unroll
            for (int r = 0; r < 4; r++) {
                int row = bm + wm + i * 16 + quad * 4 + r;
                int col = bn + wn + j * 16 + l16;
                if (CF32)
                    ((float*)Cp)[(size_t)row * N + col] = acc[i][j][r];
                else
                    ((ushort_t*)Cp)[(size_t)row * N + col] = f2bf(acc[i][j][r]);
            }
}

// ---------------------------------------------------------------------------
// RoPE standalone (fallback path only)
// ---------------------------------------------------------------------------
__global__ __launch_bounds__(256) void rope_kernel(
    ushort_t* __restrict__ qkv, const float* __restrict__ cs,
    const float* __restrict__ sn) {
    int idx = blockIdx.x * 256 + threadIdx.x;
    if (idx >= S_LEN * (NQH + NKVH)) return;
    int s  = idx / (NQH + NKVH);
    int hh = idx - s * (NQH + NKVH);

    ushort_t* p = &qkv[(size_t)s * QKV_O + hh * HD];
    const uint4* p4 = (const uint4*)p;
    float v[HD], c[HD], sv[HD];
    #pragma unroll
    for (int b = 0; b < 8; b++) unpack8(&v[b * 8], p4[b]);
    const float4* c4 = (const float4*)&cs[s * HD];
    const float4* s4 = (const float4*)&sn[s * HD];
    #pragma unroll
    for (int b = 0; b < 16; b++) {
        ((float4*)c)[b]  = c4[b];
        ((float4*)sv)[b] = s4[b];
    }
    float o[HD];
    #pragma unroll
    for (int d = 0; d < 32; d++) {
        o[d]      = v[d] * c[d]           - v[d + 32] * sv[d];
        o[d + 32] = v[d + 32] * c[d + 32] + v[d]      * sv[d + 32];
    }
    unsigned int* pw = (unsigned int*)p;
    #pragma unroll
    for (int d = 0; d < HD; d += 2)
        pw[d >> 1] = pk_bf16(o[d], o[d + 1]);
}

// ---------------------------------------------------------------------------
// attn_v5: fallback-path kernel (reads V from qkv)
// ---------------------------------------------------------------------------
__global__ __launch_bounds__(256) void attn_v5(
    const ushort_t* __restrict__ qkv, ushort_t* __restrict__ O) {
    const int bx   = blockIdx.x;
    const int h    = bx & 31;
    const int p    = bx >> 5;
    const int kvh  = h >> 2;
    const int q0d  = (31 - p) * 64;
    const int q0s  = p * 64;
    const int tid  = threadIdx.x;
    const int wave = tid >> 6;
    const int lane = tid & 63;
    const int quad = lane >> 4;
    const int l16  = lane & 15;

    __shared__ __align__(16) ushort_t Ks[2][64][72];
    __shared__ __align__(16) ushort_t Vt[2][64][72];
    __shared__ __align__(16) ushort_t Pl[4][32][72];

    const int rowbase0 = q0d + wave * 16;
    const int rowbase1 = q0s + wave * 16;

    bf16x8 bq[2][2];
    #pragma unroll
    for (int mi = 0; mi < 2; mi++) {
        const int rb = (mi == 0) ? rowbase0 : rowbase1;
        #pragma unroll
        for (int ks = 0; ks < 2; ks++) {
            uint4 u = *(const uint4*)&qkv[(size_t)(rb + l16) * QKV_O
                                          + h * HD + ks * 32 + quad * 8];
            float f[8]; unpack8(f, u);
            uint4 w = make_uint4(
                pk_bf16(f[0] * 0.125f, f[1] * 0.125f),
                pk_bf16(f[2] * 0.125f, f[3] * 0.125f),
                pk_bf16(f[4] * 0.125f, f[5] * 0.125f),
                pk_bf16(f[6] * 0.125f, f[7] * 0.125f));
            __builtin_memcpy(&bq[mi][ks], &w, 16);
        }
    }

    bf16x8 ones;
    #pragma unroll
    for (int e = 0; e < 8; e++) ones[e] = (__bf16)1.0f;

    f32x4 acc_o[2][4];
    f32x4 acc_l[2];
    #pragma unroll
    for (int mi = 0; mi < 2; mi++) {
        f32x4 z = {0.f, 0.f, 0.f, 0.f};
        acc_l[mi] = z;
        #pragma unroll
        for (int n = 0; n < 4; n++) acc_o[mi][n] = z;
    }

    const int nt = 32 - p;
    const int sr = tid >> 2;
    const int sc = (tid & 3) << 4;

    {
        const ushort_t* kp = &qkv[(size_t)sr * QKV_O + K_COL + kvh * HD + sc];
        *(uint4*)&Ks[0][sr][sc]     = *(const uint4*)kp;
        *(uint4*)&Ks[0][sr][sc + 8] = *(const uint4*)(kp + 8);
        const ushort_t* vp = &qkv[(size_t)sr * QKV_O + V_COL + kvh * HD + sc];
        ushort_t tmp[16];
        *(uint4*)&tmp[0] = *(const uint4*)vp;
        *(uint4*)&tmp[8] = *(const uint4*)(vp + 8);
        #pragma unroll
        for (int e = 0; e < 16; e++) {
            int d = sc + e;
            Vt[0][d][(sr + 8 * (d >> 3)) & 63] = tmp[e];
        }
    }
    __syncthreads();

    for (int t = 0; t < nt; t++) {
        const int cur = t & 1, nxt = cur ^ 1;
        const int j0 = t * 64;
        const bool hasNext = (t + 1 < nt);

        uint4 ka, kb, va, vb;
        if (hasNext) {
            const size_t rbase = (size_t)(j0 + 64 + sr) * QKV_O;
            const ushort_t* kp = &qkv[rbase + K_COL + kvh * HD + sc];
            ka = *(const uint4*)kp; kb = *(const uint4*)(kp + 8);
            const ushort_t* vp = &qkv[rbase + V_COL + kvh * HD + sc];
            va = *(const uint4*)vp; vb = *(const uint4*)(vp + 8);
        }

        const bool sact = (t <= p);

        f32x4 st[2][4];
        #pragma unroll
        for (int mi = 0; mi < 2; mi++)
            #pragma unroll
            for (int nk = 0; nk < 4; nk++) {
                f32x4 z = {0.f, 0.f, 0.f, 0.f};
                st[mi][nk] = z;
            }
        #pragma unroll
        for (int ks = 0; ks < 2; ks++) {
            bf16x8 ak[4];
            #pragma unroll
            for (int nk = 0; nk < 4; nk++)
                ak[nk] = *(const bf16x8*)&Ks[cur][nk * 16 + l16][ks * 32 + quad * 8];
            #pragma unroll
            for (int mi = 0; mi < 2; mi++) {
                if (mi == 1 && !sact) continue;
                #pragma unroll
                for (int nk = 0; nk < 4; nk++)
                    st[mi][nk] = __builtin_amdgcn_mfma_f32_16x16x32_bf16(
                        ak[nk], bq[mi][ks], st[mi][nk], 0, 0, 0);
            }
        }

        #pragma unroll
        for (int mi = 0; mi < 2; mi++) {
            if (mi == 1 && !sact) continue;
            const bool diag = (mi == 0) ? (t == nt - 1) : (t == p);
            const int qrow = ((mi == 0) ? rowbase0 : rowbase1) + l16;
            #pragma unroll
            for (int nk = 0; nk < 4; nk++) {
                const int kc0 = j0 + nk * 16 + quad * 4;
                float pv[4];
                #pragma unroll
                for (int r = 0; r < 4; r++) {
                    float e = __expf(st[mi][nk][r]);
                    pv[r] = (diag && (kc0 + r > qrow)) ? 0.f : e;
                }
                uint2 w2 = make_uint2(pk_bf16(pv[0], pv[1]), pk_bf16(pv[2], pv[3]));
                *(uint2*)&Pl[wave][mi * 16 + l16][nk * 16 + quad * 4] = w2;
            }
        }

        #pragma unroll
        for (int ksp = 0; ksp < 2; ksp++) {
            bf16x8 bv[4];
            #pragma unroll
            for (int nd = 0; nd < 4; nd++) {
                const int d = nd * 16 + l16;
                bv[nd] = *(const bf16x8*)&Vt[cur][d][(ksp * 32 + quad * 8 + 8 * (d >> 3)) & 63];
            }
            #pragma unroll
            for (int mi = 0; mi < 2; mi++) {
                if (mi == 1 && !sact) continue;
                bf16x8 ap = *(const bf16x8*)&Pl[wave][mi * 16 + l16][ksp * 32 + quad * 8];
                acc_l[mi] = __builtin_amdgcn_mfma_f32_16x16x32_bf16(
                    ap, ones, acc_l[mi], 0, 0, 0);
                #pragma unroll
                for (int nd = 0; nd < 4; nd++)
                    acc_o[mi][nd] = __builtin_amdgcn_mfma_f32_16x16x32_bf16(
                        ap, bv[nd], acc_o[mi][nd], 0, 0, 0);
            }
        }

        if (hasNext) {
            *(uint4*)&Ks[nxt][sr][sc]     = ka;
            *(uint4*)&Ks[nxt][sr][sc + 8] = kb;
            ushort_t tmp[16];
            *(uint4*)&tmp[0] = va;
            *(uint4*)&tmp[8] = vb;
            #pragma unroll
            for (int e = 0; e < 16; e++) {
                int d = sc + e;
                Vt[nxt][d][(sr + 8 * (d >> 3)) & 63] = tmp[e];
            }
        }
        __syncthreads();
    }

    #pragma unroll
    for (int mi = 0; mi < 2; mi++) {
        const int rb = (mi == 0) ? rowbase0 : rowbase1;
        float inv[4];
        #pragma unroll
        for (int r = 0; r < 4; r++) inv[r] = 1.0f / acc_l[mi][r];
        #pragma unroll
        for (int nd = 0; nd < 4; nd++)
            #pragma unroll
            for (int r = 0; r < 4; r++) {
                int row = rb + quad * 4 + r;
                int col = h * HD + nd * 16 + l16;
                O[(size_t)row * (NQH * HD) + col] = f2bf(acc_o[mi][nd][r] * inv[r]);
            }
    }
}

// ---------------------------------------------------------------------------
// attn_v8 (round-13 verified form, 42.9 us): 40 KB LDS (XOR-swizzled Pl) ->
// 4 blocks/CU, whole 1024-block grid co-resident; setprio around MFMA
// clusters; dbuf DMA staging with one __syncthreads per tile.
// ---------------------------------------------------------------------------
__global__ __launch_bounds__(256, 4) void attn_v8(
    const ushort_t* __restrict__ qkv, const ushort_t* __restrict__ VtG,
    ushort_t* __restrict__ O) {
    const int bx   = blockIdx.x;            // 1024 blocks
    const int h    = bx & 31;
    const int bz   = bx >> 5;               // 0..31
    const int qi   = (bz < 16) ? (31 - bz) : (bz - 16);
    const int kvh  = h >> 2;
    const int q0   = qi * 64;
    const int tid  = threadIdx.x;
    const int wave = tid >> 6;              // 0..3
    const int lane = tid & 63;
    const int quad = lane >> 4;
    const int l16  = lane & 15;

    __shared__ __align__(16) ushort_t Ks[2][64][64];   // 16 KB (DMA, swizzled)
    __shared__ __align__(16) ushort_t Vt[2][64][64];   // 16 KB (DMA, swizzled)
    __shared__ __align__(16) ushort_t Pl[4][16][64];   // 8 KB (XOR-swizzled)

    const int rb = q0 + wave * 16;          // this wave's 16 q-rows
    const int nt = qi + 1;                  // diag tile == last tile, all waves
    const int psw = (l16 & 7) << 3;         // Pl XOR swizzle (row-derived)

    // Q B-frags (lane l16 = qrow), pre-scaled by (1/8)*log2(e) for exp2
    bf16x8 bq[2];
    #pragma unroll
    for (int ks = 0; ks < 2; ks++) {
        uint4 u = *(const uint4*)&qkv[(size_t)(rb + l16) * QKV_O
                                      + h * HD + ks * 32 + quad * 8];
        float f[8]; unpack8(f, u);
        const float QS = 0.18033688011112042f;   // 0.125 * log2(e)
        uint4 w = make_uint4(
            pk_bf16(f[0] * QS, f[1] * QS), pk_bf16(f[2] * QS, f[3] * QS),
            pk_bf16(f[4] * QS, f[5] * QS), pk_bf16(f[6] * QS, f[7] * QS));
        __builtin_memcpy(&bq[ks], &w, 16);
    }

    bf16x8 ones;
    #pragma unroll
    for (int e = 0; e < 8; e++) ones[e] = (__bf16)1.0f;

    f32x4 acc_o[4];
    f32x4 acc_l;
    {
        f32x4 z = {0.f, 0.f, 0.f, 0.f};
        acc_l = z;
        #pragma unroll
        for (int n = 0; n < 4; n++) acc_o[n] = z;
    }

    // DMA lane geometry (XOR swizzle on the source side); wave stages 16 rows
    // of K and 16 rows of V^T per tile (2 x 1KB DMA ops each).
    const int lr = lane >> 3;                 // row-in-group 0..7
    const int cg = ((lane & 7) ^ lr) << 3;    // swizzled global chunk (elems)
    const ushort_t* kbase = &qkv[(size_t)(wave * 16 + lr) * QKV_O + K_COL + kvh * HD + cg];
    const size_t    kr8   = (size_t)8 * QKV_O;
    const ushort_t* vbase = &VtG[(size_t)(kvh * HD + wave * 16 + lr) * S_LEN + cg];
    const size_t    vr8   = (size_t)8 * S_LEN;

    // ---- prologue: DMA tile 0 -> buffer 0 ----
    __builtin_amdgcn_global_load_lds(GLB(kbase),       LDSP(&Ks[0][wave * 16][0]),     16, 0, 0);
    __builtin_amdgcn_global_load_lds(GLB(kbase + kr8), LDSP(&Ks[0][wave * 16 + 8][0]), 16, 0, 0);
    __builtin_amdgcn_global_load_lds(GLB(vbase),       LDSP(&Vt[0][wave * 16][0]),     16, 0, 0);
    __builtin_amdgcn_global_load_lds(GLB(vbase + vr8), LDSP(&Vt[0][wave * 16 + 8][0]), 16, 0, 0);
    __syncthreads();

    for (int t = 0; t < nt; t++) {
        const int cur = t & 1, nxt = cur ^ 1;
        const int j0 = t * 64;

        // ---- DMA-prefetch tile t+1 -> alternate buffer (flies during compute)
        if (t + 1 < nt) {
            const size_t kj = (size_t)(j0 + 64) * QKV_O;
            __builtin_amdgcn_global_load_lds(GLB(kbase + kj),             LDSP(&Ks[nxt][wave * 16][0]),     16, 0, 0);
            __builtin_amdgcn_global_load_lds(GLB(kbase + kj + kr8),       LDSP(&Ks[nxt][wave * 16 + 8][0]), 16, 0, 0);
            __builtin_amdgcn_global_load_lds(GLB(vbase + (j0 + 64)),      LDSP(&Vt[nxt][wave * 16][0]),     16, 0, 0);
            __builtin_amdgcn_global_load_lds(GLB(vbase + (j0 + 64) + vr8),LDSP(&Vt[nxt][wave * 16 + 8][0]), 16, 0, 0);
        }

        // ---- S^T = K·Q^T (setprio: favor MFMA-entering waves) ----
        f32x4 st[4];
        #pragma unroll
        for (int nk = 0; nk < 4; nk++) {
            f32x4 z = {0.f, 0.f, 0.f, 0.f};
            st[nk] = z;
        }
        __builtin_amdgcn_s_setprio(1);
        #pragma unroll
        for (int ks = 0; ks < 2; ks++) {
            const int ca = (((ks << 2) + quad) ^ (l16 & 7)) << 3;
            bf16x8 ak[4];
            #pragma unroll
            for (int nk = 0; nk < 4; nk++)
                ak[nk] = *(const bf16x8*)&Ks[cur][nk * 16 + l16][ca];
            #pragma unroll
            for (int nk = 0; nk < 4; nk++)
                st[nk] = __builtin_amdgcn_mfma_f32_16x16x32_bf16(
                    ak[nk], bq[ks], st[nk], 0, 0, 0);
        }
        __builtin_amdgcn_s_setprio(0);

        // ---- exp2 + causal mask (diag = last tile only), b64 P stores ----
        if (t == nt - 1) {
            const int qrow = rb + l16;
            #pragma unroll
            for (int nk = 0; nk < 4; nk++) {
                const int kc0 = j0 + nk * 16 + quad * 4;
                float pv[4];
                #pragma unroll
                for (int r = 0; r < 4; r++)
                    pv[r] = (kc0 + r > qrow) ? 0.f : exp2f(st[nk][r]);
                uint2 w2 = make_uint2(pk_bf16(pv[0], pv[1]), pk_bf16(pv[2], pv[3]));
                *(uint2*)&Pl[wave][l16][(nk * 16 + quad * 4) ^ psw] = w2;
            }
        } else {
            #pragma unroll
            for (int nk = 0; nk < 4; nk++) {
                float pv[4];
                #pragma unroll
                for (int r = 0; r < 4; r++)
                    pv[r] = exp2f(st[nk][r]);
                uint2 w2 = make_uint2(pk_bf16(pv[0], pv[1]), pk_bf16(pv[2], pv[3]));
                *(uint2*)&Pl[wave][l16][(nk * 16 + quad * 4) ^ psw] = w2;
            }
        }

        // ---- l += P·1 ; O += P·V (setprio around the MFMA cluster) ----
        __builtin_amdgcn_s_setprio(1);
        #pragma unroll
        for (int ksp = 0; ksp < 2; ksp++) {
            const int ca = (((ksp << 2) + quad) ^ (l16 & 7)) << 3;
            bf16x8 bv[4];
            #pragma unroll
            for (int nd = 0; nd < 4; nd++)
                bv[nd] = *(const bf16x8*)&Vt[cur][nd * 16 + l16][ca];
            bf16x8 ap = *(const bf16x8*)&Pl[wave][l16][(ksp * 32 + quad * 8) ^ psw];
            acc_l = __builtin_amdgcn_mfma_f32_16x16x32_bf16(
                ap, ones, acc_l, 0, 0, 0);
            #pragma unroll
            for (int nd = 0; nd < 4; nd++)
                acc_o[nd] = __builtin_amdgcn_mfma_f32_16x16x32_bf16(
                    ap, bv[nd], acc_o[nd], 0, 0, 0);
        }
        __builtin_amdgcn_s_setprio(0);
        __syncthreads();   // one barrier/tile; compiler drains vmcnt here
    }

    // ---- epilogue: O / l ----
    float inv[4];
    #pragma unroll
    for (int r = 0; r < 4; r++) inv[r] = 1.0f / acc_l[r];
    #pragma unroll
    for (int nd = 0; nd < 4; nd++)
        #pragma unroll
        for (int r = 0; r < 4; r++) {
            int row = rb + quad * 4 + r;
            int col = h * HD + nd * 16 + l16;
            O[(size_t)row * (NQH * HD) + col] = f2bf(acc_o[nd][r] * inv[r]);
        }
}

// ---------------------------------------------------------------------------
extern "C" void kernel_launch(void* const* d_in, const int* in_sizes, int n_in,
                              void* d_out, int out_size, void* d_ws, size_t ws_size,
                              hipStream_t stream) {
    const float* x     = (const float*)d_in[0];  // [2048][2048] fp32
    const float* cosp  = (const float*)d_in[1];  // [2048][64]   fp32
    const float* sinp  = (const float*)d_in[2];  // [2048][64]   fp32
    const float* w_qkv = (const float*)d_in[3];  // [3072][2048] fp32
    const float* w_out = (const float*)d_in[4];  // [2048][2048] fp32
    float* out = (float*)d_out;                  // [2048][2048] fp32

    const size_t NQKV = (size_t)S_LEN * QKV_O;   // 6291456
    const size_t NH2  = (size_t)S_LEN * HID;     // 4194304
    const size_t NVT  = (size_t)(NKVH * HD) * S_LEN;  // 1048576
    const size_t need_old = 2 * (NQKV + NH2) * sizeof(ushort_t);        // 41.9 MB
    const size_t need_new = need_old + NVT * sizeof(ushort_t);          // 44.0 MB

    ushort_t* qkv = (ushort_t*)d_ws;             // bf16 [2048][3072]
    ushort_t* x_bf    = qkv + NQKV;
    ushort_t* attnO   = x_bf;                    // disjoint lifetimes
    ushort_t* wqkv_bf = x_bf + NH2;
    ushort_t* wout_bf = wqkv_bf + NQKV;
    ushort_t* VtG     = wout_bf + NH2;           // bf16 [512][2048]

    if (ws_size >= need_new) {
        convert3<<<XN8 / 256 + QN8 / 256 + ON8 / 256, 256, 0, stream>>>(
            x, w_qkv, w_out, x_bf, wqkv_bf, wout_bf);

        // 1) qkv(q,k w/ RoPE) + VtG(V^T) = x @ w_qkv^T  (64x128, dbuf)
        dim3 g1(QKV_O / 128, S_LEN / 64);
        gemm_bk64<false, true, true><<<g1, 256, 0, stream>>>(
            x_bf, wqkv_bf, qkv, S_LEN, QKV_O, HID, cosp, sinp, VtG);

        // 2) causal GQA attention (round-13 verified, 42.9 us)
        attn_v8<<<32 * NQH, 256, 0, stream>>>(qkv, VtG, attnO);

        // 3) out = attnO @ w_out^T  (64x64 tile -> 1024 blocks = 4/CU)
        dim3 g2(HID / 64, S_LEN / 64);
        gemm_n64<<<g2, 256, 0, stream>>>(
            attnO, wout_bf, out, S_LEN, HID, HID);
    } else if (ws_size >= need_old) {
        // fallback path (no VtG room)
        convert3<<<XN8 / 256 + QN8 / 256 + ON8 / 256, 256, 0, stream>>>(
            x, w_qkv, w_out, x_bf, wqkv_bf, wout_bf);

        dim3 g1(QKV_O / 128, S_LEN / 64);
        gemm_bk64<false, true, false><<<g1, 256, 0, stream>>>(
            x_bf, wqkv_bf, qkv, S_LEN, QKV_O, HID, cosp, sinp, nullptr);

        attn_v5<<<16 * NQH, 256, 0, stream>>>(qkv, attnO);

        dim3 g2(HID / 64, S_LEN / 64);
        gemm_n64<<<g2, 256, 0, stream>>>(
            attnO, wout_bf, out, S_LEN, HID, HID);
    } else {
        ushort_t* attnO2 = qkv + NQKV;

        dim3 g1(QKV_O / 128, S_LEN / 128);
        gemm_bt<true, true, false><<<g1, 256, 0, stream>>>(x, w_qkv, qkv, S_LEN, QKV_O, HID);

        int rope_threads = S_LEN * (NQH + NKVH);
        rope_kernel<<<(rope_threads + 255) / 256, 256, 0, stream>>>(qkv, cosp, sinp);

        attn_v5<<<16 * NQH, 256, 0, stream>>>(qkv, attnO2);

        dim3 g2(HID / 128, S_LEN / 128);
        gemm_bt<false, true, true><<<g2, 256, 0, stream>>>(attnO2, w_out, out, S_LEN, HID, HID);
    }
}